// Round 3
// baseline (873.268 us; speedup 1.0000x reference)
//
#include <hip/hip_runtime.h>
#include <stdint.h>

#define N_NODES 20000
#define N_EDGES 320000
#define E_TOT   (N_EDGES + N_NODES)
#define NGRAPH  64
#define DIN     64
#define DHID    128
#define NHEAD   8
#define HDIM    1024

typedef unsigned int u32;
typedef unsigned short u16;
typedef __bf16 bfx8 __attribute__((ext_vector_type(8)));
typedef float f32x4 __attribute__((ext_vector_type(4)));
typedef float f32x2 __attribute__((ext_vector_type(2)));

// fp32 -> bf16 round-to-nearest-even
__device__ __forceinline__ u16 f2bf(float f){
  u32 u = __float_as_uint(f);
  u32 r = (u + 0x7FFFu + ((u >> 16) & 1u)) >> 16;
  return (u16)r;
}
__device__ __forceinline__ float bf2f(u16 v){
  return __uint_as_float(((u32)v) << 16);
}
// unpack a u32 holding 2 bf16 (little-endian) into f32x2
__device__ __forceinline__ f32x2 up2(u32 u){
  f32x2 v;
  v.x = __uint_as_float(u << 16);
  v.y = __uint_as_float(u & 0xffff0000u);
  return v;
}

// async 16B global->LDS
typedef __attribute__((address_space(3))) u32 lds_u32_t;
typedef const __attribute__((address_space(1))) u32 glb_u32_t;
__device__ __forceinline__ void g2l16(const void* g, void* l){
  __builtin_amdgcn_global_load_lds((glb_u32_t*)(uintptr_t)g,
                                   (lds_u32_t*)(uintptr_t)l, 16, 0, 0);
}

// ---------------- Threefry-2x32 (JAX), 20 rounds ----------------
__device__ __forceinline__ u32 rotl32(u32 x, int r){ return (x<<r) | (x>>(32-r)); }

__device__ __forceinline__ void threefry2x32(u32 k0, u32 k1, u32 x0, u32 x1,
                                             u32& y0, u32& y1){
  u32 k2 = k0 ^ k1 ^ 0x1BD11BDAu;
  x0 += k0; x1 += k1;
#define TFR(r) { x0 += x1; x1 = rotl32(x1, (r)); x1 ^= x0; }
  TFR(13) TFR(15) TFR(26) TFR(6)
  x0 += k1; x1 += k2 + 1u;
  TFR(17) TFR(29) TFR(16) TFR(24)
  x0 += k2; x1 += k0 + 2u;
  TFR(13) TFR(15) TFR(26) TFR(6)
  x0 += k0; x1 += k1 + 3u;
  TFR(17) TFR(29) TFR(16) TFR(24)
  x0 += k1; x1 += k2 + 4u;
  TFR(13) TFR(15) TFR(26) TFR(6)
  x0 += k2; x1 += k0 + 5u;
#undef TFR
  y0 = x0; y1 = x1;
}

// XLA ErfInv32 (Giles polynomial); fast log via v_log_f32
__device__ __forceinline__ float erfinv_fast(float x){
  float t = fmaf(-x, x, 1.0f);     // 1 - x^2
  float w = -__logf(t);
  float p;
  if (w < 5.0f){
    w -= 2.5f;
    p = 2.81022636e-08f;
    p = fmaf(p, w, 3.43273939e-07f);
    p = fmaf(p, w, -3.5233877e-06f);
    p = fmaf(p, w, -4.39150654e-06f);
    p = fmaf(p, w, 0.00021858087f);
    p = fmaf(p, w, -0.00125372503f);
    p = fmaf(p, w, -0.00417768164f);
    p = fmaf(p, w, 0.246640727f);
    p = fmaf(p, w, 1.50140941f);
  } else {
    w = sqrtf(w) - 3.0f;
    p = -0.000200214257f;
    p = fmaf(p, w, 0.000100950558f);
    p = fmaf(p, w, 0.00134934322f);
    p = fmaf(p, w, -0.00367342844f);
    p = fmaf(p, w, 0.00573950773f);
    p = fmaf(p, w, -0.0076224613f);
    p = fmaf(p, w, 0.00943887047f);
    p = fmaf(p, w, 1.00167406f);
    p = fmaf(p, w, 2.83297682f);
  }
  return p * x;
}

__device__ __forceinline__ float jax_normal(u32 seed, u32 i){
  u32 y0, y1;
  threefry2x32(0u, seed, 0u, i, y0, y1);
  u32 bits = y0 ^ y1;
  float f = __uint_as_float((bits >> 9) | 0x3f800000u) - 1.0f;   // [0,1)
  float xx = fmaxf(-0.99999994f, fmaf(f, 2.0f, -0.99999994f));   // [lo,1)
  return 1.41421356f * erfinv_fast(xx);
}

// ---------------- prep: converts + CSR counts in ONE launch ----------------
// z=0: bootW0->bf16, z=1: bootW1->bf16, z=2: x->bf16, z=3: count atomics
__global__ __launch_bounds__(256) void prep_misc_kernel(const float* __restrict__ x,
    const float* __restrict__ W0, const float* __restrict__ W1,
    u16* __restrict__ xbf, u16* __restrict__ O0, u16* __restrict__ O1,
    const int* __restrict__ ei, const int* __restrict__ batch,
    int* __restrict__ cnt, int* __restrict__ gcnt){
  const int z = blockIdx.y;
  if (z < 3){
    const float* S = (z==0) ? W0 : (z==1) ? W1 : x;
    u16* D = (z==0) ? O0 : (z==1) ? O1 : xbf;
    const int total = (z==2) ? N_NODES*DIN : HDIM*HDIM;
    int i = (blockIdx.x*256 + threadIdx.x)*4;
    if (i < total){
      float4 v = *(const float4*)(S + i);
      D[i+0] = f2bf(v.x); D[i+1] = f2bf(v.y);
      D[i+2] = f2bf(v.z); D[i+3] = f2bf(v.w);
    }
  } else {
    int i = blockIdx.x*256 + threadIdx.x;
    if (i < N_EDGES) atomicAdd(&cnt[ei[N_EDGES + i]], 1);          // dst row
    else if (i < E_TOT) atomicAdd(&gcnt[batch[i - N_EDGES]], 1);
  }
}

// gatW0/1/2 transpose+convert; z selects.
__global__ __launch_bounds__(256) void transpose_all_kernel(
    const float* __restrict__ W0, const float* __restrict__ W1,
    const float* __restrict__ W2,
    u16* __restrict__ T0, u16* __restrict__ T1, u16* __restrict__ T2){
  const int z = blockIdx.z;
  const float* W = (z==0)?W0:(z==1)?W1:W2;
  u16* T = (z==0)?T0:(z==1)?T1:T2;
  const int K = (z==0)?DIN:HDIM;
  const int bk = blockIdx.y*32;
  if (bk >= K) return;
  __shared__ float t[32][33];
  int bn = blockIdx.x*32;
  int lx = threadIdx.x & 31, ly = threadIdx.x >> 5;   // 32 x 8
#pragma unroll
  for (int r = 0; r < 32; r += 8)
    t[ly+r][lx] = W[(size_t)(bk+ly+r)*HDIM + bn + lx];
  __syncthreads();
#pragma unroll
  for (int r = 0; r < 32; r += 8)
    T[(size_t)(bn+ly+r)*K + bk + lx] = f2bf(t[lx][ly+r]);
}

// ---------------- CSR scan (block 0, writes self-loops) + gcnt scan -------
__global__ __launch_bounds__(1024) void scan_pair_kernel(const int* __restrict__ cnt,
    int* __restrict__ rowptr, int* __restrict__ cursor, int* __restrict__ colidx,
    const int* __restrict__ gcnt, int* __restrict__ goff){
  if (blockIdx.x == 1){
    if (threadIdx.x == 0){
      int s = 0;
      for (int g = 0; g < NGRAPH; ++g){ goff[g] = s; s += gcnt[g]; }
      goff[NGRAPH] = s;
    }
    return;
  }
  __shared__ int wsum[16];
  __shared__ int carry_s;
  const int tid = threadIdx.x, lane = tid & 63, wv = tid >> 6;
  if (tid == 0){ carry_s = 0; rowptr[0] = 0; }
  __syncthreads();
  for (int base = 0; base < N_NODES; base += 1024){
    int i = base + tid;
    int v = (i < N_NODES) ? cnt[i] + 1 : 0;      // +1 self-loop
    int s = v;
#pragma unroll
    for (int off = 1; off < 64; off <<= 1){
      int t = __shfl_up(s, off);
      if (lane >= off) s += t;
    }
    if (lane == 63) wsum[wv] = s;
    __syncthreads();
    if (wv == 0 && lane < 16){
      int ws = wsum[lane];
#pragma unroll
      for (int off = 1; off < 16; off <<= 1){
        int t = __shfl_up(ws, off);
        if (lane >= off) ws += t;
      }
      wsum[lane] = ws;
    }
    __syncthreads();
    int incl = s + ((wv > 0) ? wsum[wv-1] : 0) + carry_s;
    if (i < N_NODES){
      rowptr[i+1] = incl;
      const int slot = incl - v;       // row base
      colidx[slot] = i;                // self-loop FIRST (R5 ordering anchor)
      cursor[i] = slot + 1;            // edges fill after
    }
    __syncthreads();
    if (tid == 1023) carry_s = incl;
    __syncthreads();
  }
}

__global__ __launch_bounds__(256) void fill_edges_kernel(const int* __restrict__ ei,
    int* __restrict__ cursor, int* __restrict__ colidx){
  int e = blockIdx.x*256 + threadIdx.x;
  if (e < N_EDGES){
    int s = ei[e], d = ei[N_EDGES + e];
    int p = atomicAdd(&cursor[d], 1);
    colidx[p] = s;
  }
}

// ---------------- bf16 MFMA GEMM (shared body, BK=32) ----------------
// C tile of A[M,K] @ BT[1024,K]^T (+bias fp32), bf16 out; optional fused
// attention logits (block's 128-col tile == one head; p values are the
// bf16-rounded C — identical bits to a post-hoc read of C).
__device__ __forceinline__ void gemm_tile(const u16* __restrict__ A,
    const u16* __restrict__ BT, const float* __restrict__ bias,
    u16* __restrict__ Cb, int M, int K, int bm, int bn,
    u16* As, u16* Bs,
    const float* __restrict__ asrc, const float* __restrict__ adst,
    float* __restrict__ sbuf, float* __restrict__ tbuf){
  const int tid = threadIdx.x;
  const int lane = tid & 63, w = tid >> 6;
  const int wm = (w & 1)*64, wn = (w >> 1)*64;

  const int cid0 = tid, cid1 = 256 + tid;
  const int r0 = cid0 & 127, kc0 = cid0 >> 7;
  const int r1 = cid1 & 127, kc1 = cid1 >> 7;
  int ar0 = bm + r0; if (ar0 >= M) ar0 = M - 1;
  int ar1 = bm + r1; if (ar1 >= M) ar1 = M - 1;
  const u16* ag0 = A + (size_t)ar0*K + kc0*8;
  const u16* ag1 = A + (size_t)ar1*K + kc1*8;
  const u16* bg0 = BT + (size_t)(bn + r0)*K + kc0*8;
  const u16* bg1 = BT + (size_t)(bn + r1)*K + kc1*8;
  u16* al0 = As + cid0*8;  u16* al1 = As + cid1*8;
  u16* bl0 = Bs + cid0*8;  u16* bl1 = Bs + cid1*8;

  const int rowl = lane & 15, kg = lane >> 4;
  const bfx8* ap = (const bfx8*)(As + ((size_t)kg*128 + wm + rowl)*8);
  const bfx8* bp = (const bfx8*)(Bs + ((size_t)kg*128 + wn + rowl)*8);

  f32x4 acc[4][4] = {};                       // [j][i] (operand-swapped)
  for (int k0 = 0; k0 < K; k0 += 32){
    g2l16(ag0 + k0, al0);
    g2l16(ag1 + k0, al1);
    g2l16(bg0 + k0, bl0);
    g2l16(bg1 + k0, bl1);
    __syncthreads();
    bfx8 af[4], bfr[4];
#pragma unroll
    for (int i = 0; i < 4; ++i){ af[i] = ap[i*16]; bfr[i] = bp[i*16]; }
#pragma unroll
    for (int i = 0; i < 4; ++i)
#pragma unroll
      for (int j = 0; j < 4; ++j)
        acc[j][i] = __builtin_amdgcn_mfma_f32_16x16x32_bf16(bfr[j], af[i], acc[j][i], 0, 0, 0);
    __syncthreads();
  }

  const int quad = lane >> 4;
  const bool dost = (sbuf != nullptr);
  const int head = bn >> 7;
  float sl[4] = {0.f,0.f,0.f,0.f}, tl[4] = {0.f,0.f,0.f,0.f};
#pragma unroll
  for (int j = 0; j < 4; ++j){
    const int col0 = bn + wn + j*16 + quad*4;
    float4 bv = make_float4(0.f,0.f,0.f,0.f);
    if (bias) bv = *(const float4*)(bias + col0);
    float4 av = make_float4(0.f,0.f,0.f,0.f), dv = av;
    if (dost){
      const int d0 = col0 - bn;                  // head-local dim
      av = *(const float4*)(asrc + head*DHID + d0);
      dv = *(const float4*)(adst + head*DHID + d0);
    }
#pragma unroll
    for (int i = 0; i < 4; ++i){
      const int row = bm + wm + i*16 + rowl;
      const u16 p0 = f2bf(acc[j][i][0] + bv.x);
      const u16 p1 = f2bf(acc[j][i][1] + bv.y);
      const u16 p2 = f2bf(acc[j][i][2] + bv.z);
      const u16 p3 = f2bf(acc[j][i][3] + bv.w);
      if (row < M){
        uint2 pk;
        pk.x = (u32)p0 | ((u32)p1 << 16);
        pk.y = (u32)p2 | ((u32)p3 << 16);
        *(uint2*)(Cb + (size_t)row*HDIM + col0) = pk;
      }
      if (dost){
        const float c0 = bf2f(p0), c1 = bf2f(p1), c2 = bf2f(p2), c3 = bf2f(p3);
        sl[i] = fmaf(c0, av.x, fmaf(c1, av.y, fmaf(c2, av.z, fmaf(c3, av.w, sl[i]))));
        tl[i] = fmaf(c0, dv.x, fmaf(c1, dv.y, fmaf(c2, dv.z, fmaf(c3, dv.w, tl[i]))));
      }
    }
  }
  if (dost){
#pragma unroll
    for (int i = 0; i < 4; ++i){
      sl[i] += __shfl_xor(sl[i], 16); sl[i] += __shfl_xor(sl[i], 32);
      tl[i] += __shfl_xor(tl[i], 16); tl[i] += __shfl_xor(tl[i], 32);
    }
    // cross-wave (wn) combine via dead As buffer
    float* sred = (float*)As;        // [128]
    float* tred = sred + 128;        // [128]
    if ((w >> 1) == 0 && quad == 0){
#pragma unroll
      for (int i = 0; i < 4; ++i){
        const int rl = wm + i*16 + rowl;
        sred[rl] = sl[i]; tred[rl] = tl[i];
      }
    }
    __syncthreads();
    if ((w >> 1) == 1 && quad == 0){
#pragma unroll
      for (int i = 0; i < 4; ++i){
        const int rl = wm + i*16 + rowl;
        const int row = bm + rl;
        if (row < M){
          sbuf[row*NHEAD + head] = sred[rl] + sl[i];
          tbuf[row*NHEAD + head] = tred[rl] + tl[i];
        }
      }
    }
  }
}

// main GEMM: XCD-aware swizzle (R10), fused st epilogue
__global__ __launch_bounds__(256) void gemm_bf16(
    const u16* __restrict__ A, const u16* __restrict__ BT,
    const float* __restrict__ bias, u16* __restrict__ Cb, int M, int K,
    const float* __restrict__ asrc, const float* __restrict__ adst,
    float* __restrict__ sbuf, float* __restrict__ tbuf){
  __shared__ __align__(16) u16 As[4*128*8];   // 8 KB
  __shared__ __align__(16) u16 Bs[4*128*8];   // 8 KB
  const int kblk = blockIdx.y*8 + blockIdx.x;
  const int xc = kblk & 7, bq = (kblk >> 3) & 7, gq = kblk >> 6;
  const int bmi = gq*8 + xc;                  // row-tile index
  const int mt = (M + 127) >> 7;
  if (bmi >= mt) return;
  gemm_tile(A, BT, bias, Cb, M, K, bmi*128, bq*128, As, Bs,
            asrc, adst, sbuf, tbuf);
}

// weight-fusion GEMMs (z=0,1) + fused-bias reductions (z=2) in one launch
__global__ __launch_bounds__(256) void wf_bias_kernel(
    const u16* __restrict__ A0, const u16* __restrict__ B0, u16* __restrict__ C0,
    const u16* __restrict__ A1, const u16* __restrict__ B1, u16* __restrict__ C1,
    const float* __restrict__ bb0, const u16* __restrict__ gwt0,
    const float* __restrict__ bb1, const u16* __restrict__ gwt1,
    float* __restrict__ fb0, float* __restrict__ fb1){
  __shared__ __align__(16) u16 As[4*128*8];
  __shared__ __align__(16) u16 Bs[4*128*8];
  if (blockIdx.z < 2){
    const u16* A = blockIdx.z ? A1 : A0;
    const u16* B = blockIdx.z ? B1 : B0;
    u16* C = blockIdx.z ? C1 : C0;
    gemm_tile(A, B, nullptr, C, HDIM, HDIM, blockIdx.y*128, blockIdx.x*128,
              As, Bs, nullptr, nullptr, nullptr, nullptr);
  } else {
    const int kb = blockIdx.y*8 + blockIdx.x;          // 0..63
    const int wv = threadIdx.x >> 6, lane = threadIdx.x & 63;
    for (int idx = kb*4 + wv; idx < 2*HDIM; idx += 256){
      const int set = idx >> 10, n = idx & (HDIM-1);
      const float* bb = set ? bb1 : bb0;
      const u16* row = (set ? gwt1 : gwt0) + (size_t)n*HDIM + lane*16;
      const float* bp = bb + lane*16;
      float acc = 0.f;
#pragma unroll
      for (int k = 0; k < 16; ++k) acc = fmaf(bp[k], bf2f(row[k]), acc);
      for (int off = 32; off > 0; off >>= 1) acc += __shfl_down(acc, off);
      if (lane == 0) (set ? fb1 : fb0)[n] = acc;
    }
  }
}

// ---------------- GAT aggregation: WAVE-per-node, deep-MLP chunk ----------
// lane layout, e-phase : lane = jsub*8 + hh  (8 edge slots x 8 heads)
// lane layout, agg     : lane owns dims [lane*16, lane*16+16)  -> head hA=lane>>3
// Per 8-edge chunk: issue ALL 16 row loads (256B/lane in flight) right after
// colidx; softmax shfl-chain runs in the latency shadow; fma pass last.
__global__ __launch_bounds__(256) void gat_agg_kernel(const u16* __restrict__ hlin,
    const float* __restrict__ sbuf, const float* __restrict__ tbuf,
    const int* __restrict__ rowptr, const int* __restrict__ colidx,
    const float* __restrict__ bias, float* __restrict__ outf,
    u16* __restrict__ outbf, u32 seed){
  const int tid  = threadIdx.x;
  const int lane = tid & 63;
  const int n    = blockIdx.x*4 + (tid >> 6);
  const int jsub = lane >> 3;          // edge slot in e-phase
  const int hh   = lane & 7;           // head in e-phase
  const int hA   = lane >> 3;          // head owning this lane's dims
  const int row0 = rowptr[n];
  const int deg  = rowptr[n+1] - row0; // >=1 (self-loop)
  const float tn = tbuf[n*NHEAD + hh];
  const char* hl = (const char*)hlin;
  const u32 lb   = (u32)lane << 5;     // 32 bytes per lane

  f32x2 acc[8] = {};                   // 16 dims
  float m_run = -INFINITY, d_run = 0.f;

  for (int c = 0; c < deg; c += 8){
    const int ne = min(8, deg - c);
    // ---- colidx for this chunk (clamped for pad slots) ----
    const int jj = (jsub < ne) ? jsub : (ne - 1);
    const int srcv = colidx[row0 + c + jj];
    // ---- attention-logit load (critical path to w) ----
    float e = sbuf[srcv*NHEAD + hh] + tn;
    // ---- issue ALL row loads for this chunk immediately ----
    int sA[8];
#pragma unroll
    for (int j = 0; j < 8; ++j) sA[j] = __builtin_amdgcn_readlane(srcv, j*8);
    uint4 ra[8], rb[8];
#pragma unroll
    for (int j = 0; j < 8; ++j){
      if (j < ne){                     // wave-uniform branch
        const char* rp = hl + (((size_t)(u32)sA[j]) << 11);
        ra[j] = *(const uint4*)(rp + lb);
        rb[j] = *(const uint4*)(rp + lb + 16);
      }
    }
    // ---- softmax (overlaps with in-flight row loads) ----
    e = (e > 0.f) ? e : 0.2f*e;                        // leaky_relu 0.2
    if (jsub >= ne) e = -INFINITY;
    float mc = e;
    mc = fmaxf(mc, __shfl_xor(mc, 8));
    mc = fmaxf(mc, __shfl_xor(mc, 16));
    mc = fmaxf(mc, __shfl_xor(mc, 32));
    const float mnew = fmaxf(m_run, mc);
    const float w = __expf(e - mnew);                  // exp(-inf)=0 for pads
    float ws = w;
    ws += __shfl_xor(ws, 8);
    ws += __shfl_xor(ws, 16);
    ws += __shfl_xor(ws, 32);
    const float r = (m_run == -INFINITY) ? 0.0f : __expf(m_run - mnew);
    d_run = fmaf(d_run, r, ws);
    m_run = mnew;
    // ---- rescale accumulators for this lane's head ----
    const float rA = __shfl(r, hA);
    const f32x2 r2 = {rA, rA};
#pragma unroll
    for (int q = 0; q < 8; ++q) acc[q] *= r2;
    // ---- weighted accumulate (loads arrive by now) ----
#pragma unroll
    for (int j = 0; j < 8; ++j){
      if (j < ne){                     // wave-uniform branch
        const float wj = __shfl(w, j*8 + hA);
        const f32x2 wv = {wj, wj};
        acc[0] = __builtin_elementwise_fma(wv, up2(ra[j].x), acc[0]);
        acc[1] = __builtin_elementwise_fma(wv, up2(ra[j].y), acc[1]);
        acc[2] = __builtin_elementwise_fma(wv, up2(ra[j].z), acc[2]);
        acc[3] = __builtin_elementwise_fma(wv, up2(ra[j].w), acc[3]);
        acc[4] = __builtin_elementwise_fma(wv, up2(rb[j].x), acc[4]);
        acc[5] = __builtin_elementwise_fma(wv, up2(rb[j].y), acc[5]);
        acc[6] = __builtin_elementwise_fma(wv, up2(rb[j].z), acc[6]);
        acc[7] = __builtin_elementwise_fma(wv, up2(rb[j].w), acc[7]);
      }
    }
  }

  // ---- epilogue: normalize + bias + elu (+ noise + bf16) ----
  const float dA = __shfl(d_run, hA);
  const float invA = 1.0f / fmaxf(dA, 1e-16f);
  float o[16];
#pragma unroll
  for (int q = 0; q < 8; ++q){ o[2*q] = acc[q].x; o[2*q+1] = acc[q].y; }
  const float4* bp = (const float4*)(bias + lane*16);
#pragma unroll
  for (int q = 0; q < 4; ++q){
    const float4 bv = bp[q];
    o[4*q+0] = fmaf(o[4*q+0], invA, bv.x);
    o[4*q+1] = fmaf(o[4*q+1], invA, bv.y);
    o[4*q+2] = fmaf(o[4*q+2], invA, bv.z);
    o[4*q+3] = fmaf(o[4*q+3], invA, bv.w);
  }
#pragma unroll
  for (int k = 0; k < 16; ++k)
    o[k] = (o[k] > 0.f) ? o[k] : __expf(o[k]) - 1.0f;   // elu (fast)
  if (outbf){
    const u32 ib = (u32)n*HDIM + (u32)lane*16u;
    u32 pk[8];
#pragma unroll
    for (int q = 0; q < 8; ++q){
      const float v0 = fmaf(0.1f, jax_normal(seed, ib + 2u*q + 0u), o[2*q+0]);
      const float v1 = fmaf(0.1f, jax_normal(seed, ib + 2u*q + 1u), o[2*q+1]);
      pk[q] = (u32)f2bf(v0) | ((u32)f2bf(v1) << 16);
    }
    uint4* dst = (uint4*)(outbf + (size_t)n*HDIM + lane*16);
    dst[0] = make_uint4(pk[0], pk[1], pk[2], pk[3]);
    dst[1] = make_uint4(pk[4], pk[5], pk[6], pk[7]);
  } else {
    float4* dst = (float4*)(outf + (size_t)n*HDIM + lane*16);
#pragma unroll
    for (int q = 0; q < 4; ++q)
      dst[q] = make_float4(o[4*q], o[4*q+1], o[4*q+2], o[4*q+3]);
  }
}

// ---------------- pool stage 1: partial sums over sorted batch ------------
__global__ __launch_bounds__(256) void pool_sum_kernel(const float* __restrict__ h,
    const int* __restrict__ batch, float* __restrict__ gsum){
  const int n0 = blockIdx.x*128;
  const int n1 = min(n0 + 128, N_NODES);
  const int cb = threadIdx.x*4;
  float4 acc = make_float4(0.f,0.f,0.f,0.f);
  int curg = batch[n0];
  for (int n = n0; n < n1; ++n){
    const int g = batch[n];
    if (g != curg){
      atomicAdd(&gsum[curg*HDIM + cb+0], acc.x);
      atomicAdd(&gsum[curg*HDIM + cb+1], acc.y);
      atomicAdd(&gsum[curg*HDIM + cb+2], acc.z);
      atomicAdd(&gsum[curg*HDIM + cb+3], acc.w);
      acc = make_float4(0.f,0.f,0.f,0.f);
      curg = g;
    }
    const float4 v = *(const float4*)(h + (size_t)n*HDIM + cb);
    acc.x += v.x; acc.y += v.y; acc.z += v.z; acc.w += v.w;
  }
  atomicAdd(&gsum[curg*HDIM + cb+0], acc.x);
  atomicAdd(&gsum[curg*HDIM + cb+1], acc.y);
  atomicAdd(&gsum[curg*HDIM + cb+2], acc.z);
  atomicAdd(&gsum[curg*HDIM + cb+3], acc.w);
}

// ---------------- pool stage 2: mean + classifier (reads 256KB gsum) ------
__global__ __launch_bounds__(256) void pool_clf_kernel(const float* __restrict__ gsum,
    const int* __restrict__ gcnt,
    const float* __restrict__ W1, const float* __restrict__ b1,
    const float* __restrict__ W2, const float* __restrict__ b2,
    float* __restrict__ out){
  __shared__ float gs[HDIM];
  __shared__ float z[DHID];
  const int g = blockIdx.x, tid = threadIdx.x;
  const int cb = tid*4;
  const float invc = 1.0f / fmaxf((float)gcnt[g], 1.0f);
  const float4 s = *(const float4*)(gsum + (size_t)g*HDIM + cb);
  gs[cb+0] = s.x*invc; gs[cb+1] = s.y*invc;
  gs[cb+2] = s.z*invc; gs[cb+3] = s.w*invc;
  __syncthreads();
  if (tid < DHID){
    float a = b1[tid];
    for (int k = 0; k < HDIM; ++k) a = fmaf(gs[k], W1[k*DHID + tid], a);
    z[tid] = fmaxf(a, 0.0f);
  }
  __syncthreads();
  if (tid < 2){
    float o = b2[tid];
    for (int k = 0; k < DHID; ++k) o = fmaf(z[k], W2[k*2 + tid], o);
    out[g*2 + tid] = o;
  }
}

// ---------------- launch ----------------
extern "C" void kernel_launch(void* const* d_in, const int* in_sizes, int n_in,
                              void* d_out, int out_size, void* d_ws, size_t ws_size,
                              hipStream_t stream){
  const float* x      = (const float*)d_in[0];
  const int*   ei     = (const int*)d_in[1];
  const int*   batch  = (const int*)d_in[2];
  const float* gatW[3]  = {(const float*)d_in[3],  (const float*)d_in[7],  (const float*)d_in[11]};
  const float* gatB[3]  = {(const float*)d_in[4],  (const float*)d_in[8],  (const float*)d_in[12]};
  const float* asrc[3]  = {(const float*)d_in[5],  (const float*)d_in[9],  (const float*)d_in[13]};
  const float* adst[3]  = {(const float*)d_in[6],  (const float*)d_in[10], (const float*)d_in[14]};
  const float* bootW[2] = {(const float*)d_in[15], (const float*)d_in[17]};
  const float* bootB[2] = {(const float*)d_in[16], (const float*)d_in[18]};
  const float* clfW1 = (const float*)d_in[19];
  const float* clfb1 = (const float*)d_in[20];
  const float* clfW2 = (const float*)d_in[21];
  const float* clfb2 = (const float*)d_in[22];
  float* outp = (float*)d_out;

  // ---- workspace layout ----
  float* fws  = (float*)d_ws;
  float* hB   = fws;                               // N*HD fp32 (GAT L2 out)
  float* sbuf = hB + (size_t)N_NODES*HDIM;         // N*H
  float* tbuf = sbuf + (size_t)N_NODES*NHEAD;      // N*H
  float* fbias0 = tbuf + (size_t)N_NODES*NHEAD;    // HD fp32 (bootB0 @ gatW1)
  float* fbias1 = fbias0 + HDIM;                   // HD fp32 (bootB1 @ gatW2)
  u16* xbf    = (u16*)(fbias1 + HDIM);             // N*DIN bf16
  u16* hAbf   = xbf + (size_t)N_NODES*DIN;         // N*HD bf16 (GAT linear out)
  u16* hBbf   = hAbf + (size_t)N_NODES*HDIM;       // N*HD bf16 (GAT+noise out)
  u16* wt[3];
  wt[0] = hBbf + (size_t)N_NODES*HDIM;             // gatW0^T [1024,64]
  wt[1] = wt[0] + (size_t)HDIM*DIN;                // gatW1^T [1024,1024]
  wt[2] = wt[1] + (size_t)HDIM*HDIM;               // gatW2^T
  u16* wnt0   = wt[2] + (size_t)HDIM*HDIM;         // bootW0 bf16 (row-major)
  u16* wnt1   = wnt0 + (size_t)HDIM*HDIM;          // bootW1 bf16 (row-major)
  u16* wf0    = wnt1 + (size_t)HDIM*HDIM;          // (bootW0@gatW1)^T bf16
  u16* wf1    = wf0 + (size_t)HDIM*HDIM;           // (bootW1@gatW2)^T bf16
  int* rowptr = (int*)(wf1 + (size_t)HDIM*HDIM);   // N+1
  int* cursor = rowptr + (N_NODES+1);              // N
  int* colidx = cursor + N_NODES;                  // E_TOT
  int* gcnt   = colidx + E_TOT;                    // G (start of contiguous memset)
  int* cnt    = gcnt + NGRAPH;                     // N (memset cont.)
  float* gsum = (float*)(cnt + N_NODES);           // G*HD (memset cont.)
  int* goff   = (int*)(gsum + (size_t)NGRAPH*HDIM);// G+1

  (void)hipMemsetAsync(gcnt, 0, (NGRAPH + N_NODES + NGRAPH*HDIM)*sizeof(int), stream);

  const int nb_e = (N_EDGES + 255)/256;

  // converts (x, bootW0, bootW1) + CSR/graph counts in one launch
  prep_misc_kernel<<<dim3((E_TOT + 255)/256, 4), 256, 0, stream>>>(
      x, bootW[0], bootW[1], xbf, wnt0, wnt1, ei, batch, cnt, gcnt);
  transpose_all_kernel<<<dim3(HDIM/32, HDIM/32, 3), 256, 0, stream>>>(
      gatW[0], gatW[1], gatW[2], wt[0], wt[1], wt[2]);
  scan_pair_kernel<<<2, 1024, 0, stream>>>(cnt, rowptr, cursor, colidx, gcnt, goff);
  fill_edges_kernel<<<nb_e, 256, 0, stream>>>(ei, cursor, colidx);

  // fused weights wf[n,k] = sum_m gatW^T[n,m]*bootW[k,m] + fused biases
  wf_bias_kernel<<<dim3(8, 8, 3), 256, 0, stream>>>(
      wt[1], wnt0, wf0, wt[2], wnt1, wf1,
      bootB[0], wt[1], bootB[1], wt[2], fbias0, fbias1);

  // swizzled grid: 8 col-tiles x (row-tiles padded to multiple of 8)
  const int mt = (N_NODES + 127)/128;              // 157
  dim3 gemmGrid(8, (mt + 7)/8*8);                  // (8, 160)

  // L0 (gemm with fused s/t epilogue)
  gemm_bf16<<<gemmGrid, 256, 0, stream>>>(xbf, wt[0], nullptr, hAbf, N_NODES, DIN,
                                          asrc[0], adst[0], sbuf, tbuf);
  gat_agg_kernel<<<N_NODES/4, 256, 0, stream>>>(hAbf, sbuf, tbuf, rowptr, colidx,
                                                gatB[0], nullptr, hBbf, 100u);
  // L1 (fused boot0+gat1 linear)
  gemm_bf16<<<gemmGrid, 256, 0, stream>>>(hBbf, wf0, fbias0, hAbf, N_NODES, HDIM,
                                          asrc[1], adst[1], sbuf, tbuf);
  gat_agg_kernel<<<N_NODES/4, 256, 0, stream>>>(hAbf, sbuf, tbuf, rowptr, colidx,
                                                gatB[1], nullptr, hBbf, 101u);
  // L2 (fused boot1+gat2 linear)
  gemm_bf16<<<gemmGrid, 256, 0, stream>>>(hBbf, wf1, fbias1, hAbf, N_NODES, HDIM,
                                          asrc[2], adst[2], sbuf, tbuf);
  gat_agg_kernel<<<N_NODES/4, 256, 0, stream>>>(hAbf, sbuf, tbuf, rowptr, colidx,
                                                gatB[2], hB, nullptr, 0u);

  // mean pool (2-stage) + classifier
  pool_sum_kernel<<<(N_NODES + 127)/128, 256, 0, stream>>>(hB, batch, gsum);
  pool_clf_kernel<<<NGRAPH, 256, 0, stream>>>(gsum, gcnt,
                                              clfW1, clfb1, clfW2, clfb2, outp);
}

// Round 4
// 869.966 us; speedup vs baseline: 1.0038x; 1.0038x over previous
//
#include <hip/hip_runtime.h>
#include <stdint.h>

#define N_NODES 20000
#define N_EDGES 320000
#define E_TOT   (N_EDGES + N_NODES)
#define NGRAPH  64
#define DIN     64
#define DHID    128
#define NHEAD   8
#define HDIM    1024

typedef unsigned int u32;
typedef unsigned short u16;
typedef __bf16 bfx8 __attribute__((ext_vector_type(8)));
typedef float f32x4 __attribute__((ext_vector_type(4)));
typedef float f32x2 __attribute__((ext_vector_type(2)));

// fp32 -> bf16 round-to-nearest-even
__device__ __forceinline__ u16 f2bf(float f){
  u32 u = __float_as_uint(f);
  u32 r = (u + 0x7FFFu + ((u >> 16) & 1u)) >> 16;
  return (u16)r;
}
__device__ __forceinline__ float bf2f(u16 v){
  return __uint_as_float(((u32)v) << 16);
}
// unpack a u32 holding 2 bf16 (little-endian) into f32x2
__device__ __forceinline__ f32x2 up2(u32 u){
  f32x2 v;
  v.x = __uint_as_float(u << 16);
  v.y = __uint_as_float(u & 0xffff0000u);
  return v;
}

// async 16B global->LDS
typedef __attribute__((address_space(3))) u32 lds_u32_t;
typedef const __attribute__((address_space(1))) u32 glb_u32_t;
__device__ __forceinline__ void g2l16(const void* g, void* l){
  __builtin_amdgcn_global_load_lds((glb_u32_t*)(uintptr_t)g,
                                   (lds_u32_t*)(uintptr_t)l, 16, 0, 0);
}

// ---------------- Threefry-2x32 (JAX), 20 rounds ----------------
__device__ __forceinline__ u32 rotl32(u32 x, int r){ return (x<<r) | (x>>(32-r)); }

__device__ __forceinline__ void threefry2x32(u32 k0, u32 k1, u32 x0, u32 x1,
                                             u32& y0, u32& y1){
  u32 k2 = k0 ^ k1 ^ 0x1BD11BDAu;
  x0 += k0; x1 += k1;
#define TFR(r) { x0 += x1; x1 = rotl32(x1, (r)); x1 ^= x0; }
  TFR(13) TFR(15) TFR(26) TFR(6)
  x0 += k1; x1 += k2 + 1u;
  TFR(17) TFR(29) TFR(16) TFR(24)
  x0 += k2; x1 += k0 + 2u;
  TFR(13) TFR(15) TFR(26) TFR(6)
  x0 += k0; x1 += k1 + 3u;
  TFR(17) TFR(29) TFR(16) TFR(24)
  x0 += k1; x1 += k2 + 4u;
  TFR(13) TFR(15) TFR(26) TFR(6)
  x0 += k2; x1 += k0 + 5u;
#undef TFR
  y0 = x0; y1 = x1;
}

// XLA ErfInv32 (Giles polynomial); fast log via v_log_f32
__device__ __forceinline__ float erfinv_fast(float x){
  float t = fmaf(-x, x, 1.0f);     // 1 - x^2
  float w = -__logf(t);
  float p;
  if (w < 5.0f){
    w -= 2.5f;
    p = 2.81022636e-08f;
    p = fmaf(p, w, 3.43273939e-07f);
    p = fmaf(p, w, -3.5233877e-06f);
    p = fmaf(p, w, -4.39150654e-06f);
    p = fmaf(p, w, 0.00021858087f);
    p = fmaf(p, w, -0.00125372503f);
    p = fmaf(p, w, -0.00417768164f);
    p = fmaf(p, w, 0.246640727f);
    p = fmaf(p, w, 1.50140941f);
  } else {
    w = sqrtf(w) - 3.0f;
    p = -0.000200214257f;
    p = fmaf(p, w, 0.000100950558f);
    p = fmaf(p, w, 0.00134934322f);
    p = fmaf(p, w, -0.00367342844f);
    p = fmaf(p, w, 0.00573950773f);
    p = fmaf(p, w, -0.0076224613f);
    p = fmaf(p, w, 0.00943887047f);
    p = fmaf(p, w, 1.00167406f);
    p = fmaf(p, w, 2.83297682f);
  }
  return p * x;
}

__device__ __forceinline__ float jax_normal(u32 seed, u32 i){
  u32 y0, y1;
  threefry2x32(0u, seed, 0u, i, y0, y1);
  u32 bits = y0 ^ y1;
  float f = __uint_as_float((bits >> 9) | 0x3f800000u) - 1.0f;   // [0,1)
  float xx = fmaxf(-0.99999994f, fmaf(f, 2.0f, -0.99999994f));   // [lo,1)
  return 1.41421356f * erfinv_fast(xx);
}

// ---------------- prep: converts + CSR counts + wst in ONE launch ----------
// z=0: bootW0->bf16, z=1: bootW1->bf16, z=2: x->bf16, z=3: count atomics,
// z=4 (block 0): wst[64][16] = per-head W0 . a_src/a_dst  (fp32 exact)
__global__ __launch_bounds__(256) void prep_misc_kernel(const float* __restrict__ x,
    const float* __restrict__ W0, const float* __restrict__ W1,
    u16* __restrict__ xbf, u16* __restrict__ O0, u16* __restrict__ O1,
    const int* __restrict__ ei, const int* __restrict__ batch,
    int* __restrict__ cnt, int* __restrict__ gcnt,
    const float* __restrict__ gatW0, const float* __restrict__ asrc0,
    const float* __restrict__ adst0, float* __restrict__ wst){
  const int z = blockIdx.y;
  if (z < 3){
    const float* S = (z==0) ? W0 : (z==1) ? W1 : x;
    u16* D = (z==0) ? O0 : (z==1) ? O1 : xbf;
    const int total = (z==2) ? N_NODES*DIN : HDIM*HDIM;
    int i = (blockIdx.x*256 + threadIdx.x)*4;
    if (i < total){
      float4 v = *(const float4*)(S + i);
      D[i+0] = f2bf(v.x); D[i+1] = f2bf(v.y);
      D[i+2] = f2bf(v.z); D[i+3] = f2bf(v.w);
    }
  } else if (z == 3){
    int i = blockIdx.x*256 + threadIdx.x;
    if (i < N_EDGES) atomicAdd(&cnt[ei[N_EDGES + i]], 1);          // dst row
    else if (i < E_TOT) atomicAdd(&gcnt[batch[i - N_EDGES]], 1);
  } else {
    if (blockIdx.x == 0){
      for (int o = threadIdx.x; o < DIN*16; o += 256){
        const int d = o >> 4, c = o & 15;
        const int hh = c & 7;
        const float* av = ((c < 8) ? asrc0 : adst0) + hh*DHID;
        const float* wr = gatW0 + (size_t)d*HDIM + hh*DHID;
        float a = 0.f;
        for (int k = 0; k < DHID; ++k) a = fmaf(wr[k], av[k], a);
        wst[o] = a;
      }
    }
  }
}

// s/t for layer 0 from x (fp32): s[n,h]=x[n,:].wst[:,h], t = .wst[:,8+h]
__global__ __launch_bounds__(256) void st0_kernel(const float* __restrict__ x,
    const float* __restrict__ wst, float* __restrict__ sbuf,
    float* __restrict__ tbuf){
  const int n = blockIdx.x*256 + threadIdx.x;
  if (n >= N_NODES) return;
  float acc[16];
#pragma unroll
  for (int c = 0; c < 16; ++c) acc[c] = 0.f;
  const float* xr = x + (size_t)n*DIN;
  for (int d = 0; d < DIN; d += 4){
    const float4 xv = *(const float4*)(xr + d);
    const float* w0 = wst + d*16;
#pragma unroll
    for (int c = 0; c < 16; ++c){
      acc[c] = fmaf(xv.x, w0[c],      acc[c]);
      acc[c] = fmaf(xv.y, w0[16+c],   acc[c]);
      acc[c] = fmaf(xv.z, w0[32+c],   acc[c]);
      acc[c] = fmaf(xv.w, w0[48+c],   acc[c]);
    }
  }
#pragma unroll
  for (int h = 0; h < NHEAD; ++h){
    sbuf[n*NHEAD + h] = acc[h];
    tbuf[n*NHEAD + h] = acc[8 + h];
  }
}

// gatW0/1/2 transpose+convert; z selects. z=0 writes duplicated cols [1024][128]
__global__ __launch_bounds__(256) void transpose_all_kernel(
    const float* __restrict__ W0, const float* __restrict__ W1,
    const float* __restrict__ W2,
    u16* __restrict__ T0, u16* __restrict__ T1, u16* __restrict__ T2){
  const int z = blockIdx.z;
  const float* W = (z==0)?W0:(z==1)?W1:W2;
  u16* T = (z==0)?T0:(z==1)?T1:T2;
  const int K = (z==0)?DIN:HDIM;
  const int bk = blockIdx.y*32;
  if (bk >= K) return;
  __shared__ float t[32][33];
  int bn = blockIdx.x*32;
  int lx = threadIdx.x & 31, ly = threadIdx.x >> 5;   // 32 x 8
#pragma unroll
  for (int r = 0; r < 32; r += 8)
    t[ly+r][lx] = W[(size_t)(bk+ly+r)*HDIM + bn + lx];
  __syncthreads();
#pragma unroll
  for (int r = 0; r < 32; r += 8){
    const u16 v = f2bf(t[lx][ly+r]);
    if (z == 0){
      const size_t base = (size_t)(bn+ly+r)*128 + bk + lx;
      T[base] = v; T[base + 64] = v;           // duplicated for hi/lo K=128
    } else {
      T[(size_t)(bn+ly+r)*K + bk + lx] = v;
    }
  }
}

// ---------------- CSR scan (block 0, writes self-loops) + gcnt scan -------
__global__ __launch_bounds__(1024) void scan_pair_kernel(const int* __restrict__ cnt,
    int* __restrict__ rowptr, int* __restrict__ cursor, int* __restrict__ colidx,
    const int* __restrict__ gcnt, int* __restrict__ goff){
  if (blockIdx.x == 1){
    if (threadIdx.x == 0){
      int s = 0;
      for (int g = 0; g < NGRAPH; ++g){ goff[g] = s; s += gcnt[g]; }
      goff[NGRAPH] = s;
    }
    return;
  }
  __shared__ int wsum[16];
  __shared__ int carry_s;
  const int tid = threadIdx.x, lane = tid & 63, wv = tid >> 6;
  if (tid == 0){ carry_s = 0; rowptr[0] = 0; }
  __syncthreads();
  for (int base = 0; base < N_NODES; base += 1024){
    int i = base + tid;
    int v = (i < N_NODES) ? cnt[i] + 1 : 0;      // +1 self-loop
    int s = v;
#pragma unroll
    for (int off = 1; off < 64; off <<= 1){
      int t = __shfl_up(s, off);
      if (lane >= off) s += t;
    }
    if (lane == 63) wsum[wv] = s;
    __syncthreads();
    if (wv == 0 && lane < 16){
      int ws = wsum[lane];
#pragma unroll
      for (int off = 1; off < 16; off <<= 1){
        int t = __shfl_up(ws, off);
        if (lane >= off) ws += t;
      }
      wsum[lane] = ws;
    }
    __syncthreads();
    int incl = s + ((wv > 0) ? wsum[wv-1] : 0) + carry_s;
    if (i < N_NODES){
      rowptr[i+1] = incl;
      const int slot = incl - v;       // row base
      colidx[slot] = i;                // self-loop FIRST (R5 ordering anchor)
      cursor[i] = slot + 1;            // edges fill after
    }
    __syncthreads();
    if (tid == 1023) carry_s = incl;
    __syncthreads();
  }
}

__global__ __launch_bounds__(256) void fill_edges_kernel(const int* __restrict__ ei,
    int* __restrict__ cursor, int* __restrict__ colidx){
  int e = blockIdx.x*256 + threadIdx.x;
  if (e < N_EDGES){
    int s = ei[e], d = ei[N_EDGES + e];
    int p = atomicAdd(&cursor[d], 1);
    colidx[p] = s;
  }
}

// ---------------- bf16 MFMA GEMM (shared body, BK=32) ----------------
// emode=0: bf16 C (+optional fused s/t). emode=1: elu(C+bias)+0.1*noise->bf16
__device__ __forceinline__ void gemm_tile(const u16* __restrict__ A,
    const u16* __restrict__ BT, const float* __restrict__ bias,
    u16* __restrict__ Cb, int M, int K, int bm, int bn,
    u16* As, u16* Bs,
    const float* __restrict__ asrc, const float* __restrict__ adst,
    float* __restrict__ sbuf, float* __restrict__ tbuf,
    const int emode, const u32 seed){
  const int tid = threadIdx.x;
  const int lane = tid & 63, w = tid >> 6;
  const int wm = (w & 1)*64, wn = (w >> 1)*64;

  const int cid0 = tid, cid1 = 256 + tid;
  const int r0 = cid0 & 127, kc0 = cid0 >> 7;
  const int r1 = cid1 & 127, kc1 = cid1 >> 7;
  int ar0 = bm + r0; if (ar0 >= M) ar0 = M - 1;
  int ar1 = bm + r1; if (ar1 >= M) ar1 = M - 1;
  const u16* ag0 = A + (size_t)ar0*K + kc0*8;
  const u16* ag1 = A + (size_t)ar1*K + kc1*8;
  const u16* bg0 = BT + (size_t)(bn + r0)*K + kc0*8;
  const u16* bg1 = BT + (size_t)(bn + r1)*K + kc1*8;
  u16* al0 = As + cid0*8;  u16* al1 = As + cid1*8;
  u16* bl0 = Bs + cid0*8;  u16* bl1 = Bs + cid1*8;

  const int rowl = lane & 15, kg = lane >> 4;
  const bfx8* ap = (const bfx8*)(As + ((size_t)kg*128 + wm + rowl)*8);
  const bfx8* bp = (const bfx8*)(Bs + ((size_t)kg*128 + wn + rowl)*8);

  f32x4 acc[4][4] = {};                       // [j][i] (operand-swapped)
  for (int k0 = 0; k0 < K; k0 += 32){
    g2l16(ag0 + k0, al0);
    g2l16(ag1 + k0, al1);
    g2l16(bg0 + k0, bl0);
    g2l16(bg1 + k0, bl1);
    __syncthreads();
    bfx8 af[4], bfr[4];
#pragma unroll
    for (int i = 0; i < 4; ++i){ af[i] = ap[i*16]; bfr[i] = bp[i*16]; }
#pragma unroll
    for (int i = 0; i < 4; ++i)
#pragma unroll
      for (int j = 0; j < 4; ++j)
        acc[j][i] = __builtin_amdgcn_mfma_f32_16x16x32_bf16(bfr[j], af[i], acc[j][i], 0, 0, 0);
    __syncthreads();
  }

  const int quad = lane >> 4;
  const bool dost = (sbuf != nullptr);
  const int head = bn >> 7;
  float sl[4] = {0.f,0.f,0.f,0.f}, tl[4] = {0.f,0.f,0.f,0.f};
#pragma unroll
  for (int j = 0; j < 4; ++j){
    const int col0 = bn + wn + j*16 + quad*4;
    float4 bv = make_float4(0.f,0.f,0.f,0.f);
    if (bias) bv = *(const float4*)(bias + col0);
    float4 av = make_float4(0.f,0.f,0.f,0.f), dv = av;
    if (dost){
      const int d0 = col0 - bn;                  // head-local dim
      av = *(const float4*)(asrc + head*DHID + d0);
      dv = *(const float4*)(adst + head*DHID + d0);
    }
#pragma unroll
    for (int i = 0; i < 4; ++i){
      const int row = bm + wm + i*16 + rowl;
      if (emode == 1){
        if (row < M){
          float v0 = acc[j][i][0] + bv.x;
          float v1 = acc[j][i][1] + bv.y;
          float v2 = acc[j][i][2] + bv.z;
          float v3 = acc[j][i][3] + bv.w;
          v0 = (v0 > 0.f) ? v0 : __expf(v0) - 1.0f;
          v1 = (v1 > 0.f) ? v1 : __expf(v1) - 1.0f;
          v2 = (v2 > 0.f) ? v2 : __expf(v2) - 1.0f;
          v3 = (v3 > 0.f) ? v3 : __expf(v3) - 1.0f;
          const u32 ib = (u32)row*HDIM + (u32)col0;
          v0 = fmaf(0.1f, jax_normal(seed, ib+0u), v0);
          v1 = fmaf(0.1f, jax_normal(seed, ib+1u), v1);
          v2 = fmaf(0.1f, jax_normal(seed, ib+2u), v2);
          v3 = fmaf(0.1f, jax_normal(seed, ib+3u), v3);
          uint2 pk;
          pk.x = (u32)f2bf(v0) | ((u32)f2bf(v1) << 16);
          pk.y = (u32)f2bf(v2) | ((u32)f2bf(v3) << 16);
          *(uint2*)(Cb + (size_t)row*HDIM + col0) = pk;
        }
      } else {
        const u16 p0 = f2bf(acc[j][i][0] + bv.x);
        const u16 p1 = f2bf(acc[j][i][1] + bv.y);
        const u16 p2 = f2bf(acc[j][i][2] + bv.z);
        const u16 p3 = f2bf(acc[j][i][3] + bv.w);
        if (row < M){
          uint2 pk;
          pk.x = (u32)p0 | ((u32)p1 << 16);
          pk.y = (u32)p2 | ((u32)p3 << 16);
          *(uint2*)(Cb + (size_t)row*HDIM + col0) = pk;
        }
        if (dost){
          const float c0 = bf2f(p0), c1 = bf2f(p1), c2 = bf2f(p2), c3 = bf2f(p3);
          sl[i] = fmaf(c0, av.x, fmaf(c1, av.y, fmaf(c2, av.z, fmaf(c3, av.w, sl[i]))));
          tl[i] = fmaf(c0, dv.x, fmaf(c1, dv.y, fmaf(c2, dv.z, fmaf(c3, dv.w, tl[i]))));
        }
      }
    }
  }
  if (dost){
#pragma unroll
    for (int i = 0; i < 4; ++i){
      sl[i] += __shfl_xor(sl[i], 16); sl[i] += __shfl_xor(sl[i], 32);
      tl[i] += __shfl_xor(tl[i], 16); tl[i] += __shfl_xor(tl[i], 32);
    }
    // cross-wave (wn) combine via dead As buffer
    float* sred = (float*)As;        // [128]
    float* tred = sred + 128;        // [128]
    if ((w >> 1) == 0 && quad == 0){
#pragma unroll
      for (int i = 0; i < 4; ++i){
        const int rl = wm + i*16 + rowl;
        sred[rl] = sl[i]; tred[rl] = tl[i];
      }
    }
    __syncthreads();
    if ((w >> 1) == 1 && quad == 0){
#pragma unroll
      for (int i = 0; i < 4; ++i){
        const int rl = wm + i*16 + rowl;
        const int row = bm + rl;
        if (row < M){
          sbuf[row*NHEAD + head] = sred[rl] + sl[i];
          tbuf[row*NHEAD + head] = tred[rl] + tl[i];
        }
      }
    }
  }
}

// main GEMM: XCD-aware swizzle (R10), fused st epilogue
__global__ __launch_bounds__(256) void gemm_bf16(
    const u16* __restrict__ A, const u16* __restrict__ BT,
    const float* __restrict__ bias, u16* __restrict__ Cb, int M, int K,
    const float* __restrict__ asrc, const float* __restrict__ adst,
    float* __restrict__ sbuf, float* __restrict__ tbuf){
  __shared__ __align__(16) u16 As[4*128*8];   // 8 KB
  __shared__ __align__(16) u16 Bs[4*128*8];   // 8 KB
  const int kblk = blockIdx.y*8 + blockIdx.x;
  const int xc = kblk & 7, bq = (kblk >> 3) & 7, gq = kblk >> 6;
  const int bmi = gq*8 + xc;                  // row-tile index
  const int mt = (M + 127) >> 7;
  if (bmi >= mt) return;
  gemm_tile(A, BT, bias, Cb, M, K, bmi*128, bq*128, As, Bs,
            asrc, adst, sbuf, tbuf, 0, 0u);
}

// L0 transform GEMM: per-head [N,128(hi|lo)] @ W0dup + bias -> elu -> noise
__global__ __launch_bounds__(256) void gemm_l0t(
    const u16* __restrict__ agg2, const u16* __restrict__ BT,
    const float* __restrict__ bias, u16* __restrict__ Cb, u32 seed){
  __shared__ __align__(16) u16 As[4*128*8];
  __shared__ __align__(16) u16 Bs[4*128*8];
  const int head = blockIdx.x;                // 0..7
  const int bm = blockIdx.y*128;
  gemm_tile(agg2 + (size_t)head*N_NODES*128, BT, bias, Cb, N_NODES, 128,
            bm, head*128, As, Bs, nullptr, nullptr, nullptr, nullptr,
            1, seed);
}

// weight-fusion GEMMs (z=0,1) + fused-bias reductions (z=2) in one launch
__global__ __launch_bounds__(256) void wf_bias_kernel(
    const u16* __restrict__ A0, const u16* __restrict__ B0, u16* __restrict__ C0,
    const u16* __restrict__ A1, const u16* __restrict__ B1, u16* __restrict__ C1,
    const float* __restrict__ bb0, const u16* __restrict__ gwt0,
    const float* __restrict__ bb1, const u16* __restrict__ gwt1,
    float* __restrict__ fb0, float* __restrict__ fb1){
  __shared__ __align__(16) u16 As[4*128*8];
  __shared__ __align__(16) u16 Bs[4*128*8];
  if (blockIdx.z < 2){
    const u16* A = blockIdx.z ? A1 : A0;
    const u16* B = blockIdx.z ? B1 : B0;
    u16* C = blockIdx.z ? C1 : C0;
    gemm_tile(A, B, nullptr, C, HDIM, HDIM, blockIdx.y*128, blockIdx.x*128,
              As, Bs, nullptr, nullptr, nullptr, nullptr, 0, 0u);
  } else {
    const int kb = blockIdx.y*8 + blockIdx.x;          // 0..63
    const int wv = threadIdx.x >> 6, lane = threadIdx.x & 63;
    for (int idx = kb*4 + wv; idx < 2*HDIM; idx += 256){
      const int set = idx >> 10, n = idx & (HDIM-1);
      const float* bb = set ? bb1 : bb0;
      const u16* row = (set ? gwt1 : gwt0) + (size_t)n*HDIM + lane*16;
      const float* bp = bb + lane*16;
      float acc = 0.f;
#pragma unroll
      for (int k = 0; k < 16; ++k) acc = fmaf(bp[k], bf2f(row[k]), acc);
      for (int off = 32; off > 0; off >>= 1) acc += __shfl_down(acc, off);
      if (lane == 0) (set ? fb1 : fb0)[n] = acc;
    }
  }
}

// ---------------- GAT aggregation: WAVE-per-node (R2 structure) -----------
// lane layout, e-phase : lane = jsub*8 + hh  (8 edge slots x 8 heads)
// lane layout, agg     : lane owns dims [lane*16, lane*16+16)  -> head hA=lane>>3
__global__ __launch_bounds__(256) void gat_agg_kernel(const u16* __restrict__ hlin,
    const float* __restrict__ sbuf, const float* __restrict__ tbuf,
    const int* __restrict__ rowptr, const int* __restrict__ colidx,
    const float* __restrict__ bias, float* __restrict__ outf,
    u16* __restrict__ outbf, u32 seed){
  const int tid  = threadIdx.x;
  const int lane = tid & 63;
  const int n    = blockIdx.x*4 + (tid >> 6);
  const int jsub = lane >> 3;          // edge slot in e-phase
  const int hh   = lane & 7;           // head in e-phase
  const int hA   = lane >> 3;          // head owning this lane's dims
  const int row0 = rowptr[n];
  const int deg  = rowptr[n+1] - row0; // >=1 (self-loop)
  const float tn = tbuf[n*NHEAD + hh];
  const char* hl = (const char*)hlin;
  const u32 lb   = (u32)lane << 5;     // 32 bytes per lane

  f32x2 acc[8] = {};                   // 16 dims
  float m_run = -INFINITY, d_run = 0.f;

  for (int c = 0; c < deg; c += 8){
    const int ne = min(8, deg - c);
    // ---- e-phase: this lane handles edge (c+jsub), head hh ----
    const int jj = (jsub < ne) ? jsub : (ne - 1);      // clamp (value unused)
    const int srcv = colidx[row0 + c + jj];
    float e = sbuf[srcv*NHEAD + hh] + tn;
    e = (e > 0.f) ? e : 0.2f*e;                        // leaky_relu 0.2
    if (jsub >= ne) e = -INFINITY;
    float mc = e;
    mc = fmaxf(mc, __shfl_xor(mc, 8));
    mc = fmaxf(mc, __shfl_xor(mc, 16));
    mc = fmaxf(mc, __shfl_xor(mc, 32));
    const float mnew = fmaxf(m_run, mc);
    const float w = __expf(e - mnew);                  // exp(-inf)=0 for pads
    float ws = w;
    ws += __shfl_xor(ws, 8);
    ws += __shfl_xor(ws, 16);
    ws += __shfl_xor(ws, 32);
    const float r = (m_run == -INFINITY) ? 0.0f : __expf(m_run - mnew);
    d_run = fmaf(d_run, r, ws);
    m_run = mnew;
    // ---- rescale accumulators for this lane's head ----
    const float rA = __shfl(r, hA);
    const f32x2 r2 = {rA, rA};
#pragma unroll
    for (int q = 0; q < 8; ++q) acc[q] *= r2;
    // ---- gather + weighted accumulate (2 edges / iter) ----
    int j = 0;
    for (; j + 2 <= ne; j += 2){
      const int s0 = __builtin_amdgcn_readlane(srcv, j*8);
      const int s1 = __builtin_amdgcn_readlane(srcv, j*8 + 8);
      const float w0 = __shfl(w, j*8 + hA);
      const float w1 = __shfl(w, j*8 + 8 + hA);
      const char* rp0 = hl + (((size_t)(u32)s0) << 11);
      const char* rp1 = hl + (((size_t)(u32)s1) << 11);
      const uint4 a0 = *(const uint4*)(rp0 + lb);
      const uint4 a1 = *(const uint4*)(rp0 + lb + 16);
      const uint4 b0 = *(const uint4*)(rp1 + lb);
      const uint4 b1 = *(const uint4*)(rp1 + lb + 16);
      const f32x2 w02 = {w0, w0}, w12 = {w1, w1};
      acc[0] = __builtin_elementwise_fma(w02, up2(a0.x), acc[0]);
      acc[1] = __builtin_elementwise_fma(w02, up2(a0.y), acc[1]);
      acc[2] = __builtin_elementwise_fma(w02, up2(a0.z), acc[2]);
      acc[3] = __builtin_elementwise_fma(w02, up2(a0.w), acc[3]);
      acc[4] = __builtin_elementwise_fma(w02, up2(a1.x), acc[4]);
      acc[5] = __builtin_elementwise_fma(w02, up2(a1.y), acc[5]);
      acc[6] = __builtin_elementwise_fma(w02, up2(a1.z), acc[6]);
      acc[7] = __builtin_elementwise_fma(w02, up2(a1.w), acc[7]);
      acc[0] = __builtin_elementwise_fma(w12, up2(b0.x), acc[0]);
      acc[1] = __builtin_elementwise_fma(w12, up2(b0.y), acc[1]);
      acc[2] = __builtin_elementwise_fma(w12, up2(b0.z), acc[2]);
      acc[3] = __builtin_elementwise_fma(w12, up2(b0.w), acc[3]);
      acc[4] = __builtin_elementwise_fma(w12, up2(b1.x), acc[4]);
      acc[5] = __builtin_elementwise_fma(w12, up2(b1.y), acc[5]);
      acc[6] = __builtin_elementwise_fma(w12, up2(b1.z), acc[6]);
      acc[7] = __builtin_elementwise_fma(w12, up2(b1.w), acc[7]);
    }
    if (j < ne){
      const int s0 = __builtin_amdgcn_readlane(srcv, j*8);
      const float w0 = __shfl(w, j*8 + hA);
      const char* rp0 = hl + (((size_t)(u32)s0) << 11);
      const uint4 a0 = *(const uint4*)(rp0 + lb);
      const uint4 a1 = *(const uint4*)(rp0 + lb + 16);
      const f32x2 w02 = {w0, w0};
      acc[0] = __builtin_elementwise_fma(w02, up2(a0.x), acc[0]);
      acc[1] = __builtin_elementwise_fma(w02, up2(a0.y), acc[1]);
      acc[2] = __builtin_elementwise_fma(w02, up2(a0.z), acc[2]);
      acc[3] = __builtin_elementwise_fma(w02, up2(a0.w), acc[3]);
      acc[4] = __builtin_elementwise_fma(w02, up2(a1.x), acc[4]);
      acc[5] = __builtin_elementwise_fma(w02, up2(a1.y), acc[5]);
      acc[6] = __builtin_elementwise_fma(w02, up2(a1.z), acc[6]);
      acc[7] = __builtin_elementwise_fma(w02, up2(a1.w), acc[7]);
    }
  }

  // ---- epilogue: normalize + bias + elu (+ noise + bf16) ----
  const float dA = __shfl(d_run, hA);
  const float invA = 1.0f / fmaxf(dA, 1e-16f);
  float o[16];
#pragma unroll
  for (int q = 0; q < 8; ++q){ o[2*q] = acc[q].x; o[2*q+1] = acc[q].y; }
  const float4* bp = (const float4*)(bias + lane*16);
#pragma unroll
  for (int q = 0; q < 4; ++q){
    const float4 bv = bp[q];
    o[4*q+0] = fmaf(o[4*q+0], invA, bv.x);
    o[4*q+1] = fmaf(o[4*q+1], invA, bv.y);
    o[4*q+2] = fmaf(o[4*q+2], invA, bv.z);
    o[4*q+3] = fmaf(o[4*q+3], invA, bv.w);
  }
#pragma unroll
  for (int k = 0; k < 16; ++k)
    o[k] = (o[k] > 0.f) ? o[k] : __expf(o[k]) - 1.0f;   // elu (fast)
  if (outbf){
    const u32 ib = (u32)n*HDIM + (u32)lane*16u;
    u32 pk[8];
#pragma unroll
    for (int q = 0; q < 8; ++q){
      const float v0 = fmaf(0.1f, jax_normal(seed, ib + 2u*q + 0u), o[2*q+0]);
      const float v1 = fmaf(0.1f, jax_normal(seed, ib + 2u*q + 1u), o[2*q+1]);
      pk[q] = (u32)f2bf(v0) | ((u32)f2bf(v1) << 16);
    }
    uint4* dst = (uint4*)(outbf + (size_t)n*HDIM + lane*16);
    dst[0] = make_uint4(pk[0], pk[1], pk[2], pk[3]);
    dst[1] = make_uint4(pk[4], pk[5], pk[6], pk[7]);
  } else {
    float4* dst = (float4*)(outf + (size_t)n*HDIM + lane*16);
#pragma unroll
    for (int q = 0; q < 4; ++q)
      dst[q] = make_float4(o[4*q], o[4*q+1], o[4*q+2], o[4*q+3]);
  }
}

// ---------------- L0 aggregation over x (wave-per-node) -------------------
// e-phase layout identical to gat_agg. Agg: lane owns head hA=lane>>3 and
// x dims [(lane&7)*8, +8). Gathers 128B bf16 x-rows (L2-resident).
// Output agg2[h][n][128]: cols 0:64 = bf16-hi, 64:128 = bf16-lo of fp32 agg.
__global__ __launch_bounds__(256) void agg_x_kernel(const u16* __restrict__ xbf,
    const float* __restrict__ sbuf, const float* __restrict__ tbuf,
    const int* __restrict__ rowptr, const int* __restrict__ colidx,
    u16* __restrict__ agg2){
  const int tid  = threadIdx.x;
  const int lane = tid & 63;
  const int n    = blockIdx.x*4 + (tid >> 6);
  const int jsub = lane >> 3;
  const int hh   = lane & 7;
  const int hA   = lane >> 3;
  const int row0 = rowptr[n];
  const int deg  = rowptr[n+1] - row0;
  const float tn = tbuf[n*NHEAD + hh];
  const char* xb = (const char*)xbf;
  const u32 lb   = (u32)(lane & 7) << 4;   // 16B dim-group within 128B row

  f32x2 acc[4] = {};                       // 8 dims
  float m_run = -INFINITY, d_run = 0.f;

  for (int c = 0; c < deg; c += 8){
    const int ne = min(8, deg - c);
    const int jj = (jsub < ne) ? jsub : (ne - 1);
    const int srcv = colidx[row0 + c + jj];
    float e = sbuf[srcv*NHEAD + hh] + tn;
    e = (e > 0.f) ? e : 0.2f*e;
    if (jsub >= ne) e = -INFINITY;
    float mc = e;
    mc = fmaxf(mc, __shfl_xor(mc, 8));
    mc = fmaxf(mc, __shfl_xor(mc, 16));
    mc = fmaxf(mc, __shfl_xor(mc, 32));
    const float mnew = fmaxf(m_run, mc);
    const float w = __expf(e - mnew);
    float ws = w;
    ws += __shfl_xor(ws, 8);
    ws += __shfl_xor(ws, 16);
    ws += __shfl_xor(ws, 32);
    const float r = (m_run == -INFINITY) ? 0.0f : __expf(m_run - mnew);
    d_run = fmaf(d_run, r, ws);
    m_run = mnew;
    const float rA = __shfl(r, hA);
    const f32x2 r2 = {rA, rA};
#pragma unroll
    for (int q = 0; q < 4; ++q) acc[q] *= r2;
    int j = 0;
    for (; j + 2 <= ne; j += 2){
      const int s0 = __builtin_amdgcn_readlane(srcv, j*8);
      const int s1 = __builtin_amdgcn_readlane(srcv, j*8 + 8);
      const float w0 = __shfl(w, j*8 + hA);
      const float w1 = __shfl(w, j*8 + 8 + hA);
      const uint4 a0 = *(const uint4*)(xb + (((size_t)(u32)s0) << 7) + lb);
      const uint4 b0 = *(const uint4*)(xb + (((size_t)(u32)s1) << 7) + lb);
      const f32x2 w02 = {w0, w0}, w12 = {w1, w1};
      acc[0] = __builtin_elementwise_fma(w02, up2(a0.x), acc[0]);
      acc[1] = __builtin_elementwise_fma(w02, up2(a0.y), acc[1]);
      acc[2] = __builtin_elementwise_fma(w02, up2(a0.z), acc[2]);
      acc[3] = __builtin_elementwise_fma(w02, up2(a0.w), acc[3]);
      acc[0] = __builtin_elementwise_fma(w12, up2(b0.x), acc[0]);
      acc[1] = __builtin_elementwise_fma(w12, up2(b0.y), acc[1]);
      acc[2] = __builtin_elementwise_fma(w12, up2(b0.z), acc[2]);
      acc[3] = __builtin_elementwise_fma(w12, up2(b0.w), acc[3]);
    }
    if (j < ne){
      const int s0 = __builtin_amdgcn_readlane(srcv, j*8);
      const float w0 = __shfl(w, j*8 + hA);
      const uint4 a0 = *(const uint4*)(xb + (((size_t)(u32)s0) << 7) + lb);
      const f32x2 w02 = {w0, w0};
      acc[0] = __builtin_elementwise_fma(w02, up2(a0.x), acc[0]);
      acc[1] = __builtin_elementwise_fma(w02, up2(a0.y), acc[1]);
      acc[2] = __builtin_elementwise_fma(w02, up2(a0.z), acc[2]);
      acc[3] = __builtin_elementwise_fma(w02, up2(a0.w), acc[3]);
    }
  }

  // ---- epilogue: normalize, hi/lo bf16 split, store ----
  const float dA = __shfl(d_run, hA);
  const float invA = 1.0f / fmaxf(dA, 1e-16f);
  float v[8];
#pragma unroll
  for (int q = 0; q < 4; ++q){ v[2*q] = acc[q].x*invA; v[2*q+1] = acc[q].y*invA; }
  u32 hp[4], lp[4];
#pragma unroll
  for (int q = 0; q < 4; ++q){
    const u16 h0 = f2bf(v[2*q]),   h1 = f2bf(v[2*q+1]);
    const u16 l0 = f2bf(v[2*q]   - bf2f(h0));
    const u16 l1 = f2bf(v[2*q+1] - bf2f(h1));
    hp[q] = (u32)h0 | ((u32)h1 << 16);
    lp[q] = (u32)l0 | ((u32)l1 << 16);
  }
  u16* base = agg2 + ((size_t)hA*N_NODES + (size_t)n)*128 + (lane & 7)*8;
  *(uint4*)(base)      = make_uint4(hp[0], hp[1], hp[2], hp[3]);
  *(uint4*)(base + 64) = make_uint4(lp[0], lp[1], lp[2], lp[3]);
}

// ---------------- pool stage 1: partial sums over sorted batch ------------
__global__ __launch_bounds__(256) void pool_sum_kernel(const float* __restrict__ h,
    const int* __restrict__ batch, float* __restrict__ gsum){
  const int n0 = blockIdx.x*128;
  const int n1 = min(n0 + 128, N_NODES);
  const int cb = threadIdx.x*4;
  float4 acc = make_float4(0.f,0.f,0.f,0.f);
  int curg = batch[n0];
  for (int n = n0; n < n1; ++n){
    const int g = batch[n];
    if (g != curg){
      atomicAdd(&gsum[curg*HDIM + cb+0], acc.x);
      atomicAdd(&gsum[curg*HDIM + cb+1], acc.y);
      atomicAdd(&gsum[curg*HDIM + cb+2], acc.z);
      atomicAdd(&gsum[curg*HDIM + cb+3], acc.w);
      acc = make_float4(0.f,0.f,0.f,0.f);
      curg = g;
    }
    const float4 v = *(const float4*)(h + (size_t)n*HDIM + cb);
    acc.x += v.x; acc.y += v.y; acc.z += v.z; acc.w += v.w;
  }
  atomicAdd(&gsum[curg*HDIM + cb+0], acc.x);
  atomicAdd(&gsum[curg*HDIM + cb+1], acc.y);
  atomicAdd(&gsum[curg*HDIM + cb+2], acc.z);
  atomicAdd(&gsum[curg*HDIM + cb+3], acc.w);
}

// ---------------- pool stage 2: mean + classifier (reads 256KB gsum) ------
__global__ __launch_bounds__(256) void pool_clf_kernel(const float* __restrict__ gsum,
    const int* __restrict__ gcnt,
    const float* __restrict__ W1, const float* __restrict__ b1,
    const float* __restrict__ W2, const float* __restrict__ b2,
    float* __restrict__ out){
  __shared__ float gs[HDIM];
  __shared__ float z[DHID];
  const int g = blockIdx.x, tid = threadIdx.x;
  const int cb = tid*4;
  const float invc = 1.0f / fmaxf((float)gcnt[g], 1.0f);
  const float4 s = *(const float4*)(gsum + (size_t)g*HDIM + cb);
  gs[cb+0] = s.x*invc; gs[cb+1] = s.y*invc;
  gs[cb+2] = s.z*invc; gs[cb+3] = s.w*invc;
  __syncthreads();
  if (tid < DHID){
    float a = b1[tid];
    for (int k = 0; k < HDIM; ++k) a = fmaf(gs[k], W1[k*DHID + tid], a);
    z[tid] = fmaxf(a, 0.0f);
  }
  __syncthreads();
  if (tid < 2){
    float o = b2[tid];
    for (int k = 0; k < DHID; ++k) o = fmaf(z[k], W2[k*2 + tid], o);
    out[g*2 + tid] = o;
  }
}

// ---------------- launch ----------------
extern "C" void kernel_launch(void* const* d_in, const int* in_sizes, int n_in,
                              void* d_out, int out_size, void* d_ws, size_t ws_size,
                              hipStream_t stream){
  const float* x      = (const float*)d_in[0];
  const int*   ei     = (const int*)d_in[1];
  const int*   batch  = (const int*)d_in[2];
  const float* gatW[3]  = {(const float*)d_in[3],  (const float*)d_in[7],  (const float*)d_in[11]};
  const float* gatB[3]  = {(const float*)d_in[4],  (const float*)d_in[8],  (const float*)d_in[12]};
  const float* asrc[3]  = {(const float*)d_in[5],  (const float*)d_in[9],  (const float*)d_in[13]};
  const float* adst[3]  = {(const float*)d_in[6],  (const float*)d_in[10], (const float*)d_in[14]};
  const float* bootW[2] = {(const float*)d_in[15], (const float*)d_in[17]};
  const float* bootB[2] = {(const float*)d_in[16], (const float*)d_in[18]};
  const float* clfW1 = (const float*)d_in[19];
  const float* clfb1 = (const float*)d_in[20];
  const float* clfW2 = (const float*)d_in[21];
  const float* clfb2 = (const float*)d_in[22];
  float* outp = (float*)d_out;

  // ---- workspace layout ----
  float* fws  = (float*)d_ws;
  float* hB   = fws;                               // N*HD fp32 (GAT L2 out)
  float* sbuf = hB + (size_t)N_NODES*HDIM;         // N*H
  float* tbuf = sbuf + (size_t)N_NODES*NHEAD;      // N*H
  float* fbias0 = tbuf + (size_t)N_NODES*NHEAD;    // HD fp32 (bootB0 @ gatW1)
  float* fbias1 = fbias0 + HDIM;                   // HD fp32 (bootB1 @ gatW2)
  u16* xbf    = (u16*)(fbias1 + HDIM);             // N*DIN bf16
  u16* hAbf   = xbf + (size_t)N_NODES*DIN;         // N*HD bf16 (agg2 alias / GEMM out)
  u16* hBbf   = hAbf + (size_t)N_NODES*HDIM;       // N*HD bf16 (GAT+noise out)
  u16* wt[3];
  wt[0] = hBbf + (size_t)N_NODES*HDIM;             // gatW0^T dup [1024,128]
  wt[1] = wt[0] + (size_t)HDIM*128;                // gatW1^T [1024,1024]
  wt[2] = wt[1] + (size_t)HDIM*HDIM;               // gatW2^T
  u16* wnt0   = wt[2] + (size_t)HDIM*HDIM;         // bootW0 bf16 (row-major)
  u16* wnt1   = wnt0 + (size_t)HDIM*HDIM;          // bootW1 bf16 (row-major)
  u16* wf0    = wnt1 + (size_t)HDIM*HDIM;          // (bootW0@gatW1)^T bf16
  u16* wf1    = wf0 + (size_t)HDIM*HDIM;           // (bootW1@gatW2)^T bf16
  int* rowptr = (int*)(wf1 + (size_t)HDIM*HDIM);   // N+1
  int* cursor = rowptr + (N_NODES+1);              // N
  int* colidx = cursor + N_NODES;                  // E_TOT
  int* gcnt   = colidx + E_TOT;                    // G (start of contiguous memset)
  int* cnt    = gcnt + NGRAPH;                     // N (memset cont.)
  float* gsum = (float*)(cnt + N_NODES);           // G*HD (memset cont.)
  int* goff   = (int*)(gsum + (size_t)NGRAPH*HDIM);// G+1
  float* wst  = (float*)(goff + NGRAPH + 1);       // 64*16 fp32

  u16* agg2 = hAbf;                                // [8][N][128] bf16 (hi|lo)

  (void)hipMemsetAsync(gcnt, 0, (NGRAPH + N_NODES + NGRAPH*HDIM)*sizeof(int), stream);

  const int nb_e = (N_EDGES + 255)/256;

  // converts (x, bootW0, bootW1) + CSR/graph counts + wst in one launch
  prep_misc_kernel<<<dim3((E_TOT + 255)/256, 5), 256, 0, stream>>>(
      x, bootW[0], bootW[1], xbf, wnt0, wnt1, ei, batch, cnt, gcnt,
      gatW[0], asrc[0], adst[0], wst);
  // L0 s/t directly from fp32 x (more accurate than bf16-h path)
  st0_kernel<<<(N_NODES + 255)/256, 256, 0, stream>>>(x, wst, sbuf, tbuf);
  transpose_all_kernel<<<dim3(HDIM/32, HDIM/32, 3), 256, 0, stream>>>(
      gatW[0], gatW[1], gatW[2], wt[0], wt[1], wt[2]);
  scan_pair_kernel<<<2, 1024, 0, stream>>>(cnt, rowptr, cursor, colidx, gcnt, goff);
  fill_edges_kernel<<<nb_e, 256, 0, stream>>>(ei, cursor, colidx);

  // fused weights wf[n,k] = sum_m gatW^T[n,m]*bootW[k,m] + fused biases
  wf_bias_kernel<<<dim3(8, 8, 3), 256, 0, stream>>>(
      wt[1], wnt0, wf0, wt[2], wnt1, wf1,
      bootB[0], wt[1], bootB[1], wt[2], fbias0, fbias1);

  // swizzled grid: 8 col-tiles x (row-tiles padded to multiple of 8)
  const int mt = (N_NODES + 127)/128;              // 157
  dim3 gemmGrid(8, (mt + 7)/8*8);                  // (8, 160)

  // ---- L0: aggregate-then-transform (gathers 128B x-rows, L2-resident) ----
  agg_x_kernel<<<N_NODES/4, 256, 0, stream>>>(xbf, sbuf, tbuf, rowptr, colidx,
                                              agg2);
  gemm_l0t<<<dim3(8, mt), 256, 0, stream>>>(agg2, wt[0], gatB[0], hBbf, 100u);

  // L1 (fused boot0+gat1 linear)
  gemm_bf16<<<gemmGrid, 256, 0, stream>>>(hBbf, wf0, fbias0, hAbf, N_NODES, HDIM,
                                          asrc[1], adst[1], sbuf, tbuf);
  gat_agg_kernel<<<N_NODES/4, 256, 0, stream>>>(hAbf, sbuf, tbuf, rowptr, colidx,
                                                gatB[1], nullptr, hBbf, 101u);
  // L2 (fused boot1+gat2 linear)
  gemm_bf16<<<gemmGrid, 256, 0, stream>>>(hBbf, wf1, fbias1, hAbf, N_NODES, HDIM,
                                          asrc[2], adst[2], sbuf, tbuf);
  gat_agg_kernel<<<N_NODES/4, 256, 0, stream>>>(hAbf, sbuf, tbuf, rowptr, colidx,
                                                gatB[2], hB, nullptr, 0u);

  // mean pool (2-stage) + classifier
  pool_sum_kernel<<<(N_NODES + 127)/128, 256, 0, stream>>>(hB, batch, gsum);
  pool_clf_kernel<<<NGRAPH, 256, 0, stream>>>(gsum, gcnt,
                                              clfW1, clfb1, clfW2, clfb2, outp);
}

// Round 5
// 832.777 us; speedup vs baseline: 1.0486x; 1.0447x over previous
//
#include <hip/hip_runtime.h>
#include <stdint.h>

#define N_NODES 20000
#define N_EDGES 320000
#define E_TOT   (N_EDGES + N_NODES)
#define NGRAPH  64
#define DIN     64
#define DHID    128
#define NHEAD   8
#define HDIM    1024

typedef unsigned int u32;
typedef unsigned short u16;
typedef __bf16 bfx8 __attribute__((ext_vector_type(8)));
typedef float f32x4 __attribute__((ext_vector_type(4)));
typedef float f32x2 __attribute__((ext_vector_type(2)));

// fp32 -> bf16 round-to-nearest-even
__device__ __forceinline__ u16 f2bf(float f){
  u32 u = __float_as_uint(f);
  u32 r = (u + 0x7FFFu + ((u >> 16) & 1u)) >> 16;
  return (u16)r;
}
__device__ __forceinline__ float bf2f(u16 v){
  return __uint_as_float(((u32)v) << 16);
}
// unpack a u32 holding 2 bf16 (little-endian) into f32x2
__device__ __forceinline__ f32x2 up2(u32 u){
  f32x2 v;
  v.x = __uint_as_float(u << 16);
  v.y = __uint_as_float(u & 0xffff0000u);
  return v;
}

// async 16B global->LDS
typedef __attribute__((address_space(3))) u32 lds_u32_t;
typedef const __attribute__((address_space(1))) u32 glb_u32_t;
__device__ __forceinline__ void g2l16(const void* g, void* l){
  __builtin_amdgcn_global_load_lds((glb_u32_t*)(uintptr_t)g,
                                   (lds_u32_t*)(uintptr_t)l, 16, 0, 0);
}

// ---------------- Threefry-2x32 (JAX), 20 rounds ----------------
__device__ __forceinline__ u32 rotl32(u32 x, int r){ return (x<<r) | (x>>(32-r)); }

__device__ __forceinline__ void threefry2x32(u32 k0, u32 k1, u32 x0, u32 x1,
                                             u32& y0, u32& y1){
  u32 k2 = k0 ^ k1 ^ 0x1BD11BDAu;
  x0 += k0; x1 += k1;
#define TFR(r) { x0 += x1; x1 = rotl32(x1, (r)); x1 ^= x0; }
  TFR(13) TFR(15) TFR(26) TFR(6)
  x0 += k1; x1 += k2 + 1u;
  TFR(17) TFR(29) TFR(16) TFR(24)
  x0 += k2; x1 += k0 + 2u;
  TFR(13) TFR(15) TFR(26) TFR(6)
  x0 += k0; x1 += k1 + 3u;
  TFR(17) TFR(29) TFR(16) TFR(24)
  x0 += k1; x1 += k2 + 4u;
  TFR(13) TFR(15) TFR(26) TFR(6)
  x0 += k2; x1 += k0 + 5u;
#undef TFR
  y0 = x0; y1 = x1;
}

// XLA ErfInv32 (Giles polynomial); fast log via v_log_f32
__device__ __forceinline__ float erfinv_fast(float x){
  float t = fmaf(-x, x, 1.0f);     // 1 - x^2
  float w = -__logf(t);
  float p;
  if (w < 5.0f){
    w -= 2.5f;
    p = 2.81022636e-08f;
    p = fmaf(p, w, 3.43273939e-07f);
    p = fmaf(p, w, -3.5233877e-06f);
    p = fmaf(p, w, -4.39150654e-06f);
    p = fmaf(p, w, 0.00021858087f);
    p = fmaf(p, w, -0.00125372503f);
    p = fmaf(p, w, -0.00417768164f);
    p = fmaf(p, w, 0.246640727f);
    p = fmaf(p, w, 1.50140941f);
  } else {
    w = sqrtf(w) - 3.0f;
    p = -0.000200214257f;
    p = fmaf(p, w, 0.000100950558f);
    p = fmaf(p, w, 0.00134934322f);
    p = fmaf(p, w, -0.00367342844f);
    p = fmaf(p, w, 0.00573950773f);
    p = fmaf(p, w, -0.0076224613f);
    p = fmaf(p, w, 0.00943887047f);
    p = fmaf(p, w, 1.00167406f);
    p = fmaf(p, w, 2.83297682f);
  }
  return p * x;
}

__device__ __forceinline__ float jax_normal(u32 seed, u32 i){
  u32 y0, y1;
  threefry2x32(0u, seed, 0u, i, y0, y1);
  u32 bits = y0 ^ y1;
  float f = __uint_as_float((bits >> 9) | 0x3f800000u) - 1.0f;   // [0,1)
  float xx = fmaxf(-0.99999994f, fmaf(f, 2.0f, -0.99999994f));   // [lo,1)
  return 1.41421356f * erfinv_fast(xx);
}

// ---------------- prep: converts + CSR counts + wst in ONE launch ----------
// z=0: bootW0->bf16, z=1: bootW1->bf16, z=2: x->bf16, z=3: count atomics,
// z=4 (block 0): wst[64][16] = per-head W0 . a_src/a_dst  (fp32 exact)
__global__ __launch_bounds__(256) void prep_misc_kernel(const float* __restrict__ x,
    const float* __restrict__ W0, const float* __restrict__ W1,
    u16* __restrict__ xbf, u16* __restrict__ O0, u16* __restrict__ O1,
    const int* __restrict__ ei, const int* __restrict__ batch,
    int* __restrict__ cnt, int* __restrict__ gcnt,
    const float* __restrict__ gatW0, const float* __restrict__ asrc0,
    const float* __restrict__ adst0, float* __restrict__ wst){
  const int z = blockIdx.y;
  if (z < 3){
    const float* S = (z==0) ? W0 : (z==1) ? W1 : x;
    u16* D = (z==0) ? O0 : (z==1) ? O1 : xbf;
    const int total = (z==2) ? N_NODES*DIN : HDIM*HDIM;
    int i = (blockIdx.x*256 + threadIdx.x)*4;
    if (i < total){
      float4 v = *(const float4*)(S + i);
      D[i+0] = f2bf(v.x); D[i+1] = f2bf(v.y);
      D[i+2] = f2bf(v.z); D[i+3] = f2bf(v.w);
    }
  } else if (z == 3){
    int i = blockIdx.x*256 + threadIdx.x;
    if (i < N_EDGES) atomicAdd(&cnt[ei[N_EDGES + i]], 1);          // dst row
    else if (i < E_TOT) atomicAdd(&gcnt[batch[i - N_EDGES]], 1);
  } else {
    if (blockIdx.x == 0){
      for (int o = threadIdx.x; o < DIN*16; o += 256){
        const int d = o >> 4, c = o & 15;
        const int hh = c & 7;
        const float* av = ((c < 8) ? asrc0 : adst0) + hh*DHID;
        const float* wr = gatW0 + (size_t)d*HDIM + hh*DHID;
        float a = 0.f;
        for (int k = 0; k < DHID; ++k) a = fmaf(wr[k], av[k], a);
        wst[o] = a;
      }
    }
  }
}

// s/t for layer 0 from x (fp32): s[n,h]=x[n,:].wst[:,h], t = .wst[:,8+h]
__global__ __launch_bounds__(256) void st0_kernel(const float* __restrict__ x,
    const float* __restrict__ wst, float* __restrict__ sbuf,
    float* __restrict__ tbuf){
  const int n = blockIdx.x*256 + threadIdx.x;
  if (n >= N_NODES) return;
  float acc[16];
#pragma unroll
  for (int c = 0; c < 16; ++c) acc[c] = 0.f;
  const float* xr = x + (size_t)n*DIN;
  for (int d = 0; d < DIN; d += 4){
    const float4 xv = *(const float4*)(xr + d);
    const float* w0 = wst + d*16;
#pragma unroll
    for (int c = 0; c < 16; ++c){
      acc[c] = fmaf(xv.x, w0[c],      acc[c]);
      acc[c] = fmaf(xv.y, w0[16+c],   acc[c]);
      acc[c] = fmaf(xv.z, w0[32+c],   acc[c]);
      acc[c] = fmaf(xv.w, w0[48+c],   acc[c]);
    }
  }
#pragma unroll
  for (int h = 0; h < NHEAD; ++h){
    sbuf[n*NHEAD + h] = acc[h];
    tbuf[n*NHEAD + h] = acc[8 + h];
  }
}

// gatW0/1/2 transpose+convert; z selects. z=0 writes duplicated cols [1024][128]
__global__ __launch_bounds__(256) void transpose_all_kernel(
    const float* __restrict__ W0, const float* __restrict__ W1,
    const float* __restrict__ W2,
    u16* __restrict__ T0, u16* __restrict__ T1, u16* __restrict__ T2){
  const int z = blockIdx.z;
  const float* W = (z==0)?W0:(z==1)?W1:W2;
  u16* T = (z==0)?T0:(z==1)?T1:T2;
  const int K = (z==0)?DIN:HDIM;
  const int bk = blockIdx.y*32;
  if (bk >= K) return;
  __shared__ float t[32][33];
  int bn = blockIdx.x*32;
  int lx = threadIdx.x & 31, ly = threadIdx.x >> 5;   // 32 x 8
#pragma unroll
  for (int r = 0; r < 32; r += 8)
    t[ly+r][lx] = W[(size_t)(bk+ly+r)*HDIM + bn + lx];
  __syncthreads();
#pragma unroll
  for (int r = 0; r < 32; r += 8){
    const u16 v = f2bf(t[lx][ly+r]);
    if (z == 0){
      const size_t base = (size_t)(bn+ly+r)*128 + bk + lx;
      T[base] = v; T[base + 64] = v;           // duplicated for hi/lo K=128
    } else {
      T[(size_t)(bn+ly+r)*K + bk + lx] = v;
    }
  }
}

// ---------------- CSR scan (block 0, writes self-loops) + gcnt scan -------
__global__ __launch_bounds__(1024) void scan_pair_kernel(const int* __restrict__ cnt,
    int* __restrict__ rowptr, int* __restrict__ cursor, int* __restrict__ colidx,
    const int* __restrict__ gcnt, int* __restrict__ goff){
  if (blockIdx.x == 1){
    if (threadIdx.x == 0){
      int s = 0;
      for (int g = 0; g < NGRAPH; ++g){ goff[g] = s; s += gcnt[g]; }
      goff[NGRAPH] = s;
    }
    return;
  }
  __shared__ int wsum[16];
  __shared__ int carry_s;
  const int tid = threadIdx.x, lane = tid & 63, wv = tid >> 6;
  if (tid == 0){ carry_s = 0; rowptr[0] = 0; }
  __syncthreads();
  for (int base = 0; base < N_NODES; base += 1024){
    int i = base + tid;
    int v = (i < N_NODES) ? cnt[i] + 1 : 0;      // +1 self-loop
    int s = v;
#pragma unroll
    for (int off = 1; off < 64; off <<= 1){
      int t = __shfl_up(s, off);
      if (lane >= off) s += t;
    }
    if (lane == 63) wsum[wv] = s;
    __syncthreads();
    if (wv == 0 && lane < 16){
      int ws = wsum[lane];
#pragma unroll
      for (int off = 1; off < 16; off <<= 1){
        int t = __shfl_up(ws, off);
        if (lane >= off) ws += t;
      }
      wsum[lane] = ws;
    }
    __syncthreads();
    int incl = s + ((wv > 0) ? wsum[wv-1] : 0) + carry_s;
    if (i < N_NODES){
      rowptr[i+1] = incl;
      const int slot = incl - v;       // row base
      colidx[slot] = i;                // self-loop FIRST (R5 ordering anchor)
      cursor[i] = slot + 1;            // edges fill after
    }
    __syncthreads();
    if (tid == 1023) carry_s = incl;
    __syncthreads();
  }
}

__global__ __launch_bounds__(256) void fill_edges_kernel(const int* __restrict__ ei,
    int* __restrict__ cursor, int* __restrict__ colidx){
  int e = blockIdx.x*256 + threadIdx.x;
  if (e < N_EDGES){
    int s = ei[e], d = ei[N_EDGES + e];
    int p = atomicAdd(&cursor[d], 1);
    colidx[p] = s;
  }
}

// ---------------- bf16 MFMA GEMM (shared body, BK=32) ----------------
// emode=0: bf16 C (+optional fused s/t). emode=1: elu(C+bias)+0.1*noise->bf16
__device__ __forceinline__ void gemm_tile(const u16* __restrict__ A,
    const u16* __restrict__ BT, const float* __restrict__ bias,
    u16* __restrict__ Cb, int M, int K, int bm, int bn,
    u16* As, u16* Bs,
    const float* __restrict__ asrc, const float* __restrict__ adst,
    float* __restrict__ sbuf, float* __restrict__ tbuf,
    const int emode, const u32 seed){
  const int tid = threadIdx.x;
  const int lane = tid & 63, w = tid >> 6;
  const int wm = (w & 1)*64, wn = (w >> 1)*64;

  const int cid0 = tid, cid1 = 256 + tid;
  const int r0 = cid0 & 127, kc0 = cid0 >> 7;
  const int r1 = cid1 & 127, kc1 = cid1 >> 7;
  int ar0 = bm + r0; if (ar0 >= M) ar0 = M - 1;
  int ar1 = bm + r1; if (ar1 >= M) ar1 = M - 1;
  const u16* ag0 = A + (size_t)ar0*K + kc0*8;
  const u16* ag1 = A + (size_t)ar1*K + kc1*8;
  const u16* bg0 = BT + (size_t)(bn + r0)*K + kc0*8;
  const u16* bg1 = BT + (size_t)(bn + r1)*K + kc1*8;
  u16* al0 = As + cid0*8;  u16* al1 = As + cid1*8;
  u16* bl0 = Bs + cid0*8;  u16* bl1 = Bs + cid1*8;

  const int rowl = lane & 15, kg = lane >> 4;
  const bfx8* ap = (const bfx8*)(As + ((size_t)kg*128 + wm + rowl)*8);
  const bfx8* bp = (const bfx8*)(Bs + ((size_t)kg*128 + wn + rowl)*8);

  f32x4 acc[4][4] = {};                       // [j][i] (operand-swapped)
  for (int k0 = 0; k0 < K; k0 += 32){
    g2l16(ag0 + k0, al0);
    g2l16(ag1 + k0, al1);
    g2l16(bg0 + k0, bl0);
    g2l16(bg1 + k0, bl1);
    __syncthreads();
    bfx8 af[4], bfr[4];
#pragma unroll
    for (int i = 0; i < 4; ++i){ af[i] = ap[i*16]; bfr[i] = bp[i*16]; }
#pragma unroll
    for (int i = 0; i < 4; ++i)
#pragma unroll
      for (int j = 0; j < 4; ++j)
        acc[j][i] = __builtin_amdgcn_mfma_f32_16x16x32_bf16(bfr[j], af[i], acc[j][i], 0, 0, 0);
    __syncthreads();
  }

  const int quad = lane >> 4;
  const bool dost = (sbuf != nullptr);
  const int head = bn >> 7;
  float sl[4] = {0.f,0.f,0.f,0.f}, tl[4] = {0.f,0.f,0.f,0.f};
#pragma unroll
  for (int j = 0; j < 4; ++j){
    const int col0 = bn + wn + j*16 + quad*4;
    float4 bv = make_float4(0.f,0.f,0.f,0.f);
    if (bias) bv = *(const float4*)(bias + col0);
    float4 av = make_float4(0.f,0.f,0.f,0.f), dv = av;
    if (dost){
      const int d0 = col0 - bn;                  // head-local dim
      av = *(const float4*)(asrc + head*DHID + d0);
      dv = *(const float4*)(adst + head*DHID + d0);
    }
#pragma unroll
    for (int i = 0; i < 4; ++i){
      const int row = bm + wm + i*16 + rowl;
      if (emode == 1){
        if (row < M){
          float v0 = acc[j][i][0] + bv.x;
          float v1 = acc[j][i][1] + bv.y;
          float v2 = acc[j][i][2] + bv.z;
          float v3 = acc[j][i][3] + bv.w;
          v0 = (v0 > 0.f) ? v0 : __expf(v0) - 1.0f;
          v1 = (v1 > 0.f) ? v1 : __expf(v1) - 1.0f;
          v2 = (v2 > 0.f) ? v2 : __expf(v2) - 1.0f;
          v3 = (v3 > 0.f) ? v3 : __expf(v3) - 1.0f;
          const u32 ib = (u32)row*HDIM + (u32)col0;
          v0 = fmaf(0.1f, jax_normal(seed, ib+0u), v0);
          v1 = fmaf(0.1f, jax_normal(seed, ib+1u), v1);
          v2 = fmaf(0.1f, jax_normal(seed, ib+2u), v2);
          v3 = fmaf(0.1f, jax_normal(seed, ib+3u), v3);
          uint2 pk;
          pk.x = (u32)f2bf(v0) | ((u32)f2bf(v1) << 16);
          pk.y = (u32)f2bf(v2) | ((u32)f2bf(v3) << 16);
          *(uint2*)(Cb + (size_t)row*HDIM + col0) = pk;
        }
      } else {
        const u16 p0 = f2bf(acc[j][i][0] + bv.x);
        const u16 p1 = f2bf(acc[j][i][1] + bv.y);
        const u16 p2 = f2bf(acc[j][i][2] + bv.z);
        const u16 p3 = f2bf(acc[j][i][3] + bv.w);
        if (row < M){
          uint2 pk;
          pk.x = (u32)p0 | ((u32)p1 << 16);
          pk.y = (u32)p2 | ((u32)p3 << 16);
          *(uint2*)(Cb + (size_t)row*HDIM + col0) = pk;
        }
        if (dost){
          const float c0 = bf2f(p0), c1 = bf2f(p1), c2 = bf2f(p2), c3 = bf2f(p3);
          sl[i] = fmaf(c0, av.x, fmaf(c1, av.y, fmaf(c2, av.z, fmaf(c3, av.w, sl[i]))));
          tl[i] = fmaf(c0, dv.x, fmaf(c1, dv.y, fmaf(c2, dv.z, fmaf(c3, dv.w, tl[i]))));
        }
      }
    }
  }
  if (dost){
#pragma unroll
    for (int i = 0; i < 4; ++i){
      sl[i] += __shfl_xor(sl[i], 16); sl[i] += __shfl_xor(sl[i], 32);
      tl[i] += __shfl_xor(tl[i], 16); tl[i] += __shfl_xor(tl[i], 32);
    }
    // cross-wave (wn) combine via dead As buffer
    float* sred = (float*)As;        // [128]
    float* tred = sred + 128;        // [128]
    if ((w >> 1) == 0 && quad == 0){
#pragma unroll
      for (int i = 0; i < 4; ++i){
        const int rl = wm + i*16 + rowl;
        sred[rl] = sl[i]; tred[rl] = tl[i];
      }
    }
    __syncthreads();
    if ((w >> 1) == 1 && quad == 0){
#pragma unroll
      for (int i = 0; i < 4; ++i){
        const int rl = wm + i*16 + rowl;
        const int row = bm + rl;
        if (row < M){
          sbuf[row*NHEAD + head] = sred[rl] + sl[i];
          tbuf[row*NHEAD + head] = tred[rl] + tl[i];
        }
      }
    }
  }
}

// main GEMM: XCD-aware swizzle (R10), fused st epilogue
__global__ __launch_bounds__(256) void gemm_bf16(
    const u16* __restrict__ A, const u16* __restrict__ BT,
    const float* __restrict__ bias, u16* __restrict__ Cb, int M, int K,
    const float* __restrict__ asrc, const float* __restrict__ adst,
    float* __restrict__ sbuf, float* __restrict__ tbuf){
  __shared__ __align__(16) u16 As[4*128*8];   // 8 KB
  __shared__ __align__(16) u16 Bs[4*128*8];   // 8 KB
  const int kblk = blockIdx.y*8 + blockIdx.x;
  const int xc = kblk & 7, bq = (kblk >> 3) & 7, gq = kblk >> 6;
  const int bmi = gq*8 + xc;                  // row-tile index
  const int mt = (M + 127) >> 7;
  if (bmi >= mt) return;
  gemm_tile(A, BT, bias, Cb, M, K, bmi*128, bq*128, As, Bs,
            asrc, adst, sbuf, tbuf, 0, 0u);
}

// L0 transform GEMM: per-head [N,128(hi|lo)] @ W0dup + bias -> elu -> noise
__global__ __launch_bounds__(256) void gemm_l0t(
    const u16* __restrict__ agg2, const u16* __restrict__ BT,
    const float* __restrict__ bias, u16* __restrict__ Cb, u32 seed){
  __shared__ __align__(16) u16 As[4*128*8];
  __shared__ __align__(16) u16 Bs[4*128*8];
  const int head = blockIdx.x;                // 0..7
  const int bm = blockIdx.y*128;
  gemm_tile(agg2 + (size_t)head*N_NODES*128, BT, bias, Cb, N_NODES, 128,
            bm, head*128, As, Bs, nullptr, nullptr, nullptr, nullptr,
            1, seed);
}

// weight-fusion GEMMs (z=0,1) + fused-bias reductions (z=2) in one launch
__global__ __launch_bounds__(256) void wf_bias_kernel(
    const u16* __restrict__ A0, const u16* __restrict__ B0, u16* __restrict__ C0,
    const u16* __restrict__ A1, const u16* __restrict__ B1, u16* __restrict__ C1,
    const float* __restrict__ bb0, const u16* __restrict__ gwt0,
    const float* __restrict__ bb1, const u16* __restrict__ gwt1,
    float* __restrict__ fb0, float* __restrict__ fb1){
  __shared__ __align__(16) u16 As[4*128*8];
  __shared__ __align__(16) u16 Bs[4*128*8];
  if (blockIdx.z < 2){
    const u16* A = blockIdx.z ? A1 : A0;
    const u16* B = blockIdx.z ? B1 : B0;
    u16* C = blockIdx.z ? C1 : C0;
    gemm_tile(A, B, nullptr, C, HDIM, HDIM, blockIdx.y*128, blockIdx.x*128,
              As, Bs, nullptr, nullptr, nullptr, nullptr, 0, 0u);
  } else {
    const int kb = blockIdx.y*8 + blockIdx.x;          // 0..63
    const int wv = threadIdx.x >> 6, lane = threadIdx.x & 63;
    for (int idx = kb*4 + wv; idx < 2*HDIM; idx += 256){
      const int set = idx >> 10, n = idx & (HDIM-1);
      const float* bb = set ? bb1 : bb0;
      const u16* row = (set ? gwt1 : gwt0) + (size_t)n*HDIM + lane*16;
      const float* bp = bb + lane*16;
      float acc = 0.f;
#pragma unroll
      for (int k = 0; k < 16; ++k) acc = fmaf(bp[k], bf2f(row[k]), acc);
      for (int off = 32; off > 0; off >>= 1) acc += __shfl_down(acc, off);
      if (lane == 0) (set ? fb1 : fb0)[n] = acc;
    }
  }
}

// ---------------- GAT aggregation: WAVE-per-node (R2 structure) -----------
// lane layout, e-phase : lane = jsub*8 + hh  (8 edge slots x 8 heads)
// lane layout, agg     : lane owns dims [lane*16, lane*16+16)  -> head hA=lane>>3
// outbf != null : noise epilogue -> bf16 (layers 0/1)
// outbf == null : FUSED MEAN-POOL (layer 2): block LDS-reduce + atomics to gsum
__global__ __launch_bounds__(256) void gat_agg_kernel(const u16* __restrict__ hlin,
    const float* __restrict__ sbuf, const float* __restrict__ tbuf,
    const int* __restrict__ rowptr, const int* __restrict__ colidx,
    const float* __restrict__ bias,
    const int* __restrict__ batch, float* __restrict__ gsum,
    u16* __restrict__ outbf, u32 seed){
  __shared__ float red[4][HDIM];       // 16 KB (pool path only)
  const int tid  = threadIdx.x;
  const int lane = tid & 63;
  const int wv   = tid >> 6;
  const int n    = blockIdx.x*4 + wv;
  const int jsub = lane >> 3;          // edge slot in e-phase
  const int hh   = lane & 7;           // head in e-phase
  const int hA   = lane >> 3;          // head owning this lane's dims
  const int row0 = rowptr[n];
  const int deg  = rowptr[n+1] - row0; // >=1 (self-loop)
  const float tn = tbuf[n*NHEAD + hh];
  const char* hl = (const char*)hlin;
  const u32 lb   = (u32)lane << 5;     // 32 bytes per lane

  f32x2 acc[8] = {};                   // 16 dims
  float m_run = -INFINITY, d_run = 0.f;

  for (int c = 0; c < deg; c += 8){
    const int ne = min(8, deg - c);
    // ---- e-phase: this lane handles edge (c+jsub), head hh ----
    const int jj = (jsub < ne) ? jsub : (ne - 1);      // clamp (value unused)
    const int srcv = colidx[row0 + c + jj];
    float e = sbuf[srcv*NHEAD + hh] + tn;
    e = (e > 0.f) ? e : 0.2f*e;                        // leaky_relu 0.2
    if (jsub >= ne) e = -INFINITY;
    float mc = e;
    mc = fmaxf(mc, __shfl_xor(mc, 8));
    mc = fmaxf(mc, __shfl_xor(mc, 16));
    mc = fmaxf(mc, __shfl_xor(mc, 32));
    const float mnew = fmaxf(m_run, mc);
    const float w = __expf(e - mnew);                  // exp(-inf)=0 for pads
    float ws = w;
    ws += __shfl_xor(ws, 8);
    ws += __shfl_xor(ws, 16);
    ws += __shfl_xor(ws, 32);
    const float r = (m_run == -INFINITY) ? 0.0f : __expf(m_run - mnew);
    d_run = fmaf(d_run, r, ws);
    m_run = mnew;
    // ---- rescale accumulators for this lane's head ----
    const float rA = __shfl(r, hA);
    const f32x2 r2 = {rA, rA};
#pragma unroll
    for (int q = 0; q < 8; ++q) acc[q] *= r2;
    // ---- gather + weighted accumulate (2 edges / iter) ----
    int j = 0;
    for (; j + 2 <= ne; j += 2){
      const int s0 = __builtin_amdgcn_readlane(srcv, j*8);
      const int s1 = __builtin_amdgcn_readlane(srcv, j*8 + 8);
      const float w0 = __shfl(w, j*8 + hA);
      const float w1 = __shfl(w, j*8 + 8 + hA);
      const char* rp0 = hl + (((size_t)(u32)s0) << 11);
      const char* rp1 = hl + (((size_t)(u32)s1) << 11);
      const uint4 a0 = *(const uint4*)(rp0 + lb);
      const uint4 a1 = *(const uint4*)(rp0 + lb + 16);
      const uint4 b0 = *(const uint4*)(rp1 + lb);
      const uint4 b1 = *(const uint4*)(rp1 + lb + 16);
      const f32x2 w02 = {w0, w0}, w12 = {w1, w1};
      acc[0] = __builtin_elementwise_fma(w02, up2(a0.x), acc[0]);
      acc[1] = __builtin_elementwise_fma(w02, up2(a0.y), acc[1]);
      acc[2] = __builtin_elementwise_fma(w02, up2(a0.z), acc[2]);
      acc[3] = __builtin_elementwise_fma(w02, up2(a0.w), acc[3]);
      acc[4] = __builtin_elementwise_fma(w02, up2(a1.x), acc[4]);
      acc[5] = __builtin_elementwise_fma(w02, up2(a1.y), acc[5]);
      acc[6] = __builtin_elementwise_fma(w02, up2(a1.z), acc[6]);
      acc[7] = __builtin_elementwise_fma(w02, up2(a1.w), acc[7]);
      acc[0] = __builtin_elementwise_fma(w12, up2(b0.x), acc[0]);
      acc[1] = __builtin_elementwise_fma(w12, up2(b0.y), acc[1]);
      acc[2] = __builtin_elementwise_fma(w12, up2(b0.z), acc[2]);
      acc[3] = __builtin_elementwise_fma(w12, up2(b0.w), acc[3]);
      acc[4] = __builtin_elementwise_fma(w12, up2(b1.x), acc[4]);
      acc[5] = __builtin_elementwise_fma(w12, up2(b1.y), acc[5]);
      acc[6] = __builtin_elementwise_fma(w12, up2(b1.z), acc[6]);
      acc[7] = __builtin_elementwise_fma(w12, up2(b1.w), acc[7]);
    }
    if (j < ne){
      const int s0 = __builtin_amdgcn_readlane(srcv, j*8);
      const float w0 = __shfl(w, j*8 + hA);
      const char* rp0 = hl + (((size_t)(u32)s0) << 11);
      const uint4 a0 = *(const uint4*)(rp0 + lb);
      const uint4 a1 = *(const uint4*)(rp0 + lb + 16);
      const f32x2 w02 = {w0, w0};
      acc[0] = __builtin_elementwise_fma(w02, up2(a0.x), acc[0]);
      acc[1] = __builtin_elementwise_fma(w02, up2(a0.y), acc[1]);
      acc[2] = __builtin_elementwise_fma(w02, up2(a0.z), acc[2]);
      acc[3] = __builtin_elementwise_fma(w02, up2(a0.w), acc[3]);
      acc[4] = __builtin_elementwise_fma(w02, up2(a1.x), acc[4]);
      acc[5] = __builtin_elementwise_fma(w02, up2(a1.y), acc[5]);
      acc[6] = __builtin_elementwise_fma(w02, up2(a1.z), acc[6]);
      acc[7] = __builtin_elementwise_fma(w02, up2(a1.w), acc[7]);
    }
  }

  // ---- epilogue: normalize + bias + elu ----
  const float dA = __shfl(d_run, hA);
  const float invA = 1.0f / fmaxf(dA, 1e-16f);
  float o[16];
#pragma unroll
  for (int q = 0; q < 8; ++q){ o[2*q] = acc[q].x; o[2*q+1] = acc[q].y; }
  const float4* bp = (const float4*)(bias + lane*16);
#pragma unroll
  for (int q = 0; q < 4; ++q){
    const float4 bv = bp[q];
    o[4*q+0] = fmaf(o[4*q+0], invA, bv.x);
    o[4*q+1] = fmaf(o[4*q+1], invA, bv.y);
    o[4*q+2] = fmaf(o[4*q+2], invA, bv.z);
    o[4*q+3] = fmaf(o[4*q+3], invA, bv.w);
  }
#pragma unroll
  for (int k = 0; k < 16; ++k)
    o[k] = (o[k] > 0.f) ? o[k] : __expf(o[k]) - 1.0f;   // elu (fast)
  if (outbf){
    const u32 ib = (u32)n*HDIM + (u32)lane*16u;
    u32 pk[8];
#pragma unroll
    for (int q = 0; q < 8; ++q){
      const float v0 = fmaf(0.1f, jax_normal(seed, ib + 2u*q + 0u), o[2*q+0]);
      const float v1 = fmaf(0.1f, jax_normal(seed, ib + 2u*q + 1u), o[2*q+1]);
      pk[q] = (u32)f2bf(v0) | ((u32)f2bf(v1) << 16);
    }
    uint4* dst = (uint4*)(outbf + (size_t)n*HDIM + lane*16);
    dst[0] = make_uint4(pk[0], pk[1], pk[2], pk[3]);
    dst[1] = make_uint4(pk[4], pk[5], pk[6], pk[7]);
  } else {
    // ---- fused mean-pool: block reduce -> atomics into gsum[g] ----
    float* rw = &red[wv][lane*16];
#pragma unroll
    for (int q = 0; q < 4; ++q)
      *(float4*)(rw + q*4) = make_float4(o[4*q], o[4*q+1], o[4*q+2], o[4*q+3]);
    __syncthreads();
    const int g0 = batch[blockIdx.x*4];
    const int g3 = batch[blockIdx.x*4 + 3];
    if (g0 == g3){
      const int d = tid*4;
      float4 s;
      s.x = red[0][d+0] + red[1][d+0] + red[2][d+0] + red[3][d+0];
      s.y = red[0][d+1] + red[1][d+1] + red[2][d+1] + red[3][d+1];
      s.z = red[0][d+2] + red[1][d+2] + red[2][d+2] + red[3][d+2];
      s.w = red[0][d+3] + red[1][d+3] + red[2][d+3] + red[3][d+3];
      float* gp = gsum + (size_t)g0*HDIM + d;
      atomicAdd(gp+0, s.x); atomicAdd(gp+1, s.y);
      atomicAdd(gp+2, s.z); atomicAdd(gp+3, s.w);
    } else {
      const int gn = batch[n];
      float* gp = gsum + (size_t)gn*HDIM + lane*16;
#pragma unroll
      for (int k = 0; k < 16; ++k) atomicAdd(gp + k, o[k]);
    }
  }
}

// ---------------- L0 aggregation over x (wave-per-node) -------------------
// e-phase layout identical to gat_agg. Agg: lane owns head hA=lane>>3 and
// x dims [(lane&7)*8, +8). Gathers 128B bf16 x-rows (L2-resident).
// Output agg2[h][n][128]: cols 0:64 = bf16-hi, 64:128 = bf16-lo of fp32 agg.
__global__ __launch_bounds__(256) void agg_x_kernel(const u16* __restrict__ xbf,
    const float* __restrict__ sbuf, const float* __restrict__ tbuf,
    const int* __restrict__ rowptr, const int* __restrict__ colidx,
    u16* __restrict__ agg2){
  const int tid  = threadIdx.x;
  const int lane = tid & 63;
  const int n    = blockIdx.x*4 + (tid >> 6);
  const int jsub = lane >> 3;
  const int hh   = lane & 7;
  const int hA   = lane >> 3;
  const int row0 = rowptr[n];
  const int deg  = rowptr[n+1] - row0;
  const float tn = tbuf[n*NHEAD + hh];
  const char* xb = (const char*)xbf;
  const u32 lb   = (u32)(lane & 7) << 4;   // 16B dim-group within 128B row

  f32x2 acc[4] = {};                       // 8 dims
  float m_run = -INFINITY, d_run = 0.f;

  for (int c = 0; c < deg; c += 8){
    const int ne = min(8, deg - c);
    const int jj = (jsub < ne) ? jsub : (ne - 1);
    const int srcv = colidx[row0 + c + jj];
    float e = sbuf[srcv*NHEAD + hh] + tn;
    e = (e > 0.f) ? e : 0.2f*e;
    if (jsub >= ne) e = -INFINITY;
    float mc = e;
    mc = fmaxf(mc, __shfl_xor(mc, 8));
    mc = fmaxf(mc, __shfl_xor(mc, 16));
    mc = fmaxf(mc, __shfl_xor(mc, 32));
    const float mnew = fmaxf(m_run, mc);
    const float w = __expf(e - mnew);
    float ws = w;
    ws += __shfl_xor(ws, 8);
    ws += __shfl_xor(ws, 16);
    ws += __shfl_xor(ws, 32);
    const float r = (m_run == -INFINITY) ? 0.0f : __expf(m_run - mnew);
    d_run = fmaf(d_run, r, ws);
    m_run = mnew;
    const float rA = __shfl(r, hA);
    const f32x2 r2 = {rA, rA};
#pragma unroll
    for (int q = 0; q < 4; ++q) acc[q] *= r2;
    int j = 0;
    for (; j + 2 <= ne; j += 2){
      const int s0 = __builtin_amdgcn_readlane(srcv, j*8);
      const int s1 = __builtin_amdgcn_readlane(srcv, j*8 + 8);
      const float w0 = __shfl(w, j*8 + hA);
      const float w1 = __shfl(w, j*8 + 8 + hA);
      const uint4 a0 = *(const uint4*)(xb + (((size_t)(u32)s0) << 7) + lb);
      const uint4 b0 = *(const uint4*)(xb + (((size_t)(u32)s1) << 7) + lb);
      const f32x2 w02 = {w0, w0}, w12 = {w1, w1};
      acc[0] = __builtin_elementwise_fma(w02, up2(a0.x), acc[0]);
      acc[1] = __builtin_elementwise_fma(w02, up2(a0.y), acc[1]);
      acc[2] = __builtin_elementwise_fma(w02, up2(a0.z), acc[2]);
      acc[3] = __builtin_elementwise_fma(w02, up2(a0.w), acc[3]);
      acc[0] = __builtin_elementwise_fma(w12, up2(b0.x), acc[0]);
      acc[1] = __builtin_elementwise_fma(w12, up2(b0.y), acc[1]);
      acc[2] = __builtin_elementwise_fma(w12, up2(b0.z), acc[2]);
      acc[3] = __builtin_elementwise_fma(w12, up2(b0.w), acc[3]);
    }
    if (j < ne){
      const int s0 = __builtin_amdgcn_readlane(srcv, j*8);
      const float w0 = __shfl(w, j*8 + hA);
      const uint4 a0 = *(const uint4*)(xb + (((size_t)(u32)s0) << 7) + lb);
      const f32x2 w02 = {w0, w0};
      acc[0] = __builtin_elementwise_fma(w02, up2(a0.x), acc[0]);
      acc[1] = __builtin_elementwise_fma(w02, up2(a0.y), acc[1]);
      acc[2] = __builtin_elementwise_fma(w02, up2(a0.z), acc[2]);
      acc[3] = __builtin_elementwise_fma(w02, up2(a0.w), acc[3]);
    }
  }

  // ---- epilogue: normalize, hi/lo bf16 split, store ----
  const float dA = __shfl(d_run, hA);
  const float invA = 1.0f / fmaxf(dA, 1e-16f);
  float v[8];
#pragma unroll
  for (int q = 0; q < 4; ++q){ v[2*q] = acc[q].x*invA; v[2*q+1] = acc[q].y*invA; }
  u32 hp[4], lp[4];
#pragma unroll
  for (int q = 0; q < 4; ++q){
    const u16 h0 = f2bf(v[2*q]),   h1 = f2bf(v[2*q+1]);
    const u16 l0 = f2bf(v[2*q]   - bf2f(h0));
    const u16 l1 = f2bf(v[2*q+1] - bf2f(h1));
    hp[q] = (u32)h0 | ((u32)h1 << 16);
    lp[q] = (u32)l0 | ((u32)l1 << 16);
  }
  u16* base = agg2 + ((size_t)hA*N_NODES + (size_t)n)*128 + (lane & 7)*8;
  *(uint4*)(base)      = make_uint4(hp[0], hp[1], hp[2], hp[3]);
  *(uint4*)(base + 64) = make_uint4(lp[0], lp[1], lp[2], lp[3]);
}

// ---------------- pool stage 2: mean + classifier (reads 256KB gsum) ------
__global__ __launch_bounds__(256) void pool_clf_kernel(const float* __restrict__ gsum,
    const int* __restrict__ gcnt,
    const float* __restrict__ W1, const float* __restrict__ b1,
    const float* __restrict__ W2, const float* __restrict__ b2,
    float* __restrict__ out){
  __shared__ float gs[HDIM];
  __shared__ float z[DHID];
  const int g = blockIdx.x, tid = threadIdx.x;
  const int cb = tid*4;
  const float invc = 1.0f / fmaxf((float)gcnt[g], 1.0f);
  const float4 s = *(const float4*)(gsum + (size_t)g*HDIM + cb);
  gs[cb+0] = s.x*invc; gs[cb+1] = s.y*invc;
  gs[cb+2] = s.z*invc; gs[cb+3] = s.w*invc;
  __syncthreads();
  if (tid < DHID){
    float a = b1[tid];
    for (int k = 0; k < HDIM; ++k) a = fmaf(gs[k], W1[k*DHID + tid], a);
    z[tid] = fmaxf(a, 0.0f);
  }
  __syncthreads();
  if (tid < 2){
    float o = b2[tid];
    for (int k = 0; k < DHID; ++k) o = fmaf(z[k], W2[k*2 + tid], o);
    out[g*2 + tid] = o;
  }
}

// ---------------- launch ----------------
extern "C" void kernel_launch(void* const* d_in, const int* in_sizes, int n_in,
                              void* d_out, int out_size, void* d_ws, size_t ws_size,
                              hipStream_t stream){
  const float* x      = (const float*)d_in[0];
  const int*   ei     = (const int*)d_in[1];
  const int*   batch  = (const int*)d_in[2];
  const float* gatW[3]  = {(const float*)d_in[3],  (const float*)d_in[7],  (const float*)d_in[11]};
  const float* gatB[3]  = {(const float*)d_in[4],  (const float*)d_in[8],  (const float*)d_in[12]};
  const float* asrc[3]  = {(const float*)d_in[5],  (const float*)d_in[9],  (const float*)d_in[13]};
  const float* adst[3]  = {(const float*)d_in[6],  (const float*)d_in[10], (const float*)d_in[14]};
  const float* bootW[2] = {(const float*)d_in[15], (const float*)d_in[17]};
  const float* bootB[2] = {(const float*)d_in[16], (const float*)d_in[18]};
  const float* clfW1 = (const float*)d_in[19];
  const float* clfb1 = (const float*)d_in[20];
  const float* clfW2 = (const float*)d_in[21];
  const float* clfb2 = (const float*)d_in[22];
  float* outp = (float*)d_out;

  // ---- workspace layout ----
  float* fws  = (float*)d_ws;
  float* hB   = fws;                               // N*HD fp32 (now unused; keeps layout)
  float* sbuf = hB + (size_t)N_NODES*HDIM;         // N*H
  float* tbuf = sbuf + (size_t)N_NODES*NHEAD;      // N*H
  float* fbias0 = tbuf + (size_t)N_NODES*NHEAD;    // HD fp32 (bootB0 @ gatW1)
  float* fbias1 = fbias0 + HDIM;                   // HD fp32 (bootB1 @ gatW2)
  u16* xbf    = (u16*)(fbias1 + HDIM);             // N*DIN bf16
  u16* hAbf   = xbf + (size_t)N_NODES*DIN;         // N*HD bf16 (agg2 alias / GEMM out)
  u16* hBbf   = hAbf + (size_t)N_NODES*HDIM;       // N*HD bf16 (GAT+noise out)
  u16* wt[3];
  wt[0] = hBbf + (size_t)N_NODES*HDIM;             // gatW0^T dup [1024,128]
  wt[1] = wt[0] + (size_t)HDIM*128;                // gatW1^T [1024,1024]
  wt[2] = wt[1] + (size_t)HDIM*HDIM;               // gatW2^T
  u16* wnt0   = wt[2] + (size_t)HDIM*HDIM;         // bootW0 bf16 (row-major)
  u16* wnt1   = wnt0 + (size_t)HDIM*HDIM;          // bootW1 bf16 (row-major)
  u16* wf0    = wnt1 + (size_t)HDIM*HDIM;          // (bootW0@gatW1)^T bf16
  u16* wf1    = wf0 + (size_t)HDIM*HDIM;           // (bootW1@gatW2)^T bf16
  int* rowptr = (int*)(wf1 + (size_t)HDIM*HDIM);   // N+1
  int* cursor = rowptr + (N_NODES+1);              // N
  int* colidx = cursor + N_NODES;                  // E_TOT
  int* gcnt   = colidx + E_TOT;                    // G (start of contiguous memset)
  int* cnt    = gcnt + NGRAPH;                     // N (memset cont.)
  float* gsum = (float*)(cnt + N_NODES);           // G*HD (memset cont.)
  int* goff   = (int*)(gsum + (size_t)NGRAPH*HDIM);// G+1
  float* wst  = (float*)(goff + NGRAPH + 1);       // 64*16 fp32

  u16* agg2 = hAbf;                                // [8][N][128] bf16 (hi|lo)

  (void)hipMemsetAsync(gcnt, 0, (NGRAPH + N_NODES + NGRAPH*HDIM)*sizeof(int), stream);

  const int nb_e = (N_EDGES + 255)/256;

  // converts (x, bootW0, bootW1) + CSR/graph counts + wst in one launch
  prep_misc_kernel<<<dim3((E_TOT + 255)/256, 5), 256, 0, stream>>>(
      x, bootW[0], bootW[1], xbf, wnt0, wnt1, ei, batch, cnt, gcnt,
      gatW[0], asrc[0], adst[0], wst);
  // L0 s/t directly from fp32 x (more accurate than bf16-h path)
  st0_kernel<<<(N_NODES + 255)/256, 256, 0, stream>>>(x, wst, sbuf, tbuf);
  transpose_all_kernel<<<dim3(HDIM/32, HDIM/32, 3), 256, 0, stream>>>(
      gatW[0], gatW[1], gatW[2], wt[0], wt[1], wt[2]);
  scan_pair_kernel<<<2, 1024, 0, stream>>>(cnt, rowptr, cursor, colidx, gcnt, goff);
  fill_edges_kernel<<<nb_e, 256, 0, stream>>>(ei, cursor, colidx);

  // fused weights wf[n,k] = sum_m gatW^T[n,m]*bootW[k,m] + fused biases
  wf_bias_kernel<<<dim3(8, 8, 3), 256, 0, stream>>>(
      wt[1], wnt0, wf0, wt[2], wnt1, wf1,
      bootB[0], wt[1], bootB[1], wt[2], fbias0, fbias1);

  // swizzled grid: 8 col-tiles x (row-tiles padded to multiple of 8)
  const int mt = (N_NODES + 127)/128;              // 157
  dim3 gemmGrid(8, (mt + 7)/8*8);                  // (8, 160)

  // ---- L0: aggregate-then-transform (gathers 128B x-rows, L2-resident) ----
  agg_x_kernel<<<N_NODES/4, 256, 0, stream>>>(xbf, sbuf, tbuf, rowptr, colidx,
                                              agg2);
  gemm_l0t<<<dim3(8, mt), 256, 0, stream>>>(agg2, wt[0], gatB[0], hBbf, 100u);

  // L1 (fused boot0+gat1 linear)
  gemm_bf16<<<gemmGrid, 256, 0, stream>>>(hBbf, wf0, fbias0, hAbf, N_NODES, HDIM,
                                          asrc[1], adst[1], sbuf, tbuf);
  gat_agg_kernel<<<N_NODES/4, 256, 0, stream>>>(hAbf, sbuf, tbuf, rowptr, colidx,
                                                gatB[1], batch, gsum, hBbf, 101u);
  // L2 (fused boot1+gat2 linear) + gat with FUSED MEAN-POOL epilogue
  gemm_bf16<<<gemmGrid, 256, 0, stream>>>(hBbf, wf1, fbias1, hAbf, N_NODES, HDIM,
                                          asrc[2], adst[2], sbuf, tbuf);
  gat_agg_kernel<<<N_NODES/4, 256, 0, stream>>>(hAbf, sbuf, tbuf, rowptr, colidx,
                                                gatB[2], batch, gsum, nullptr, 0u);

  // classifier (gsum already holds per-graph sums)
  pool_clf_kernel<<<NGRAPH, 256, 0, stream>>>(gsum, gcnt,
                                              clfW1, clfb1, clfW2, clfb2, outp);
}

// Round 6
// 829.726 us; speedup vs baseline: 1.0525x; 1.0037x over previous
//
#include <hip/hip_runtime.h>
#include <stdint.h>

#define N_NODES 20000
#define N_EDGES 320000
#define E_TOT   (N_EDGES + N_NODES)
#define NGRAPH  64
#define DIN     64
#define DHID    128
#define NHEAD   8
#define HDIM    1024

typedef unsigned int u32;
typedef unsigned short u16;
typedef __bf16 bfx8 __attribute__((ext_vector_type(8)));
typedef float f32x4 __attribute__((ext_vector_type(4)));
typedef float f32x2 __attribute__((ext_vector_type(2)));

// fp32 -> bf16 round-to-nearest-even
__device__ __forceinline__ u16 f2bf(float f){
  u32 u = __float_as_uint(f);
  u32 r = (u + 0x7FFFu + ((u >> 16) & 1u)) >> 16;
  return (u16)r;
}
__device__ __forceinline__ float bf2f(u16 v){
  return __uint_as_float(((u32)v) << 16);
}
// unpack a u32 holding 2 bf16 (little-endian) into f32x2
__device__ __forceinline__ f32x2 up2(u32 u){
  f32x2 v;
  v.x = __uint_as_float(u << 16);
  v.y = __uint_as_float(u & 0xffff0000u);
  return v;
}

// async 16B global->LDS
typedef __attribute__((address_space(3))) u32 lds_u32_t;
typedef const __attribute__((address_space(1))) u32 glb_u32_t;
__device__ __forceinline__ void g2l16(const void* g, void* l){
  __builtin_amdgcn_global_load_lds((glb_u32_t*)(uintptr_t)g,
                                   (lds_u32_t*)(uintptr_t)l, 16, 0, 0);
}

// ---------------- Threefry-2x32 (JAX), 20 rounds ----------------
__device__ __forceinline__ u32 rotl32(u32 x, int r){ return (x<<r) | (x>>(32-r)); }

__device__ __forceinline__ void threefry2x32(u32 k0, u32 k1, u32 x0, u32 x1,
                                             u32& y0, u32& y1){
  u32 k2 = k0 ^ k1 ^ 0x1BD11BDAu;
  x0 += k0; x1 += k1;
#define TFR(r) { x0 += x1; x1 = rotl32(x1, (r)); x1 ^= x0; }
  TFR(13) TFR(15) TFR(26) TFR(6)
  x0 += k1; x1 += k2 + 1u;
  TFR(17) TFR(29) TFR(16) TFR(24)
  x0 += k2; x1 += k0 + 2u;
  TFR(13) TFR(15) TFR(26) TFR(6)
  x0 += k0; x1 += k1 + 3u;
  TFR(17) TFR(29) TFR(16) TFR(24)
  x0 += k1; x1 += k2 + 4u;
  TFR(13) TFR(15) TFR(26) TFR(6)
  x0 += k2; x1 += k0 + 5u;
#undef TFR
  y0 = x0; y1 = x1;
}

// XLA ErfInv32 (Giles polynomial); fast log via v_log_f32
__device__ __forceinline__ float erfinv_fast(float x){
  float t = fmaf(-x, x, 1.0f);     // 1 - x^2
  float w = -__logf(t);
  float p;
  if (w < 5.0f){
    w -= 2.5f;
    p = 2.81022636e-08f;
    p = fmaf(p, w, 3.43273939e-07f);
    p = fmaf(p, w, -3.5233877e-06f);
    p = fmaf(p, w, -4.39150654e-06f);
    p = fmaf(p, w, 0.00021858087f);
    p = fmaf(p, w, -0.00125372503f);
    p = fmaf(p, w, -0.00417768164f);
    p = fmaf(p, w, 0.246640727f);
    p = fmaf(p, w, 1.50140941f);
  } else {
    w = sqrtf(w) - 3.0f;
    p = -0.000200214257f;
    p = fmaf(p, w, 0.000100950558f);
    p = fmaf(p, w, 0.00134934322f);
    p = fmaf(p, w, -0.00367342844f);
    p = fmaf(p, w, 0.00573950773f);
    p = fmaf(p, w, -0.0076224613f);
    p = fmaf(p, w, 0.00943887047f);
    p = fmaf(p, w, 1.00167406f);
    p = fmaf(p, w, 2.83297682f);
  }
  return p * x;
}

__device__ __forceinline__ float jax_normal(u32 seed, u32 i){
  u32 y0, y1;
  threefry2x32(0u, seed, 0u, i, y0, y1);
  u32 bits = y0 ^ y1;
  float f = __uint_as_float((bits >> 9) | 0x3f800000u) - 1.0f;   // [0,1)
  float xx = fmaxf(-0.99999994f, fmaf(f, 2.0f, -0.99999994f));   // [lo,1)
  return 1.41421356f * erfinv_fast(xx);
}

// ---------------- prep: converts + CSR counts + wst in ONE launch ----------
// z=0: bootW0->bf16, z=1: bootW1->bf16, z=2: x->bf16, z=3: count atomics,
// z=4 (block 0): wst[64][16] = per-head W0 . a_src/a_dst  (fp32 exact)
__global__ __launch_bounds__(256) void prep_misc_kernel(const float* __restrict__ x,
    const float* __restrict__ W0, const float* __restrict__ W1,
    u16* __restrict__ xbf, u16* __restrict__ O0, u16* __restrict__ O1,
    const int* __restrict__ ei, const int* __restrict__ batch,
    int* __restrict__ cnt, int* __restrict__ gcnt,
    const float* __restrict__ gatW0, const float* __restrict__ asrc0,
    const float* __restrict__ adst0, float* __restrict__ wst){
  const int z = blockIdx.y;
  if (z < 3){
    const float* S = (z==0) ? W0 : (z==1) ? W1 : x;
    u16* D = (z==0) ? O0 : (z==1) ? O1 : xbf;
    const int total = (z==2) ? N_NODES*DIN : HDIM*HDIM;
    int i = (blockIdx.x*256 + threadIdx.x)*4;
    if (i < total){
      float4 v = *(const float4*)(S + i);
      D[i+0] = f2bf(v.x); D[i+1] = f2bf(v.y);
      D[i+2] = f2bf(v.z); D[i+3] = f2bf(v.w);
    }
  } else if (z == 3){
    int i = blockIdx.x*256 + threadIdx.x;
    if (i < N_EDGES) atomicAdd(&cnt[ei[N_EDGES + i]], 1);          // dst row
    else if (i < E_TOT) atomicAdd(&gcnt[batch[i - N_EDGES]], 1);
  } else {
    if (blockIdx.x == 0){
      for (int o = threadIdx.x; o < DIN*16; o += 256){
        const int d = o >> 4, c = o & 15;
        const int hh = c & 7;
        const float* av = ((c < 8) ? asrc0 : adst0) + hh*DHID;
        const float* wr = gatW0 + (size_t)d*HDIM + hh*DHID;
        float a = 0.f;
        for (int k = 0; k < DHID; ++k) a = fmaf(wr[k], av[k], a);
        wst[o] = a;
      }
    }
  }
}

// s/t for layer 0 from x (fp32): s[n,h]=x[n,:].wst[:,h], t = .wst[:,8+h]
__global__ __launch_bounds__(256) void st0_kernel(const float* __restrict__ x,
    const float* __restrict__ wst, float* __restrict__ sbuf,
    float* __restrict__ tbuf){
  const int n = blockIdx.x*256 + threadIdx.x;
  if (n >= N_NODES) return;
  float acc[16];
#pragma unroll
  for (int c = 0; c < 16; ++c) acc[c] = 0.f;
  const float* xr = x + (size_t)n*DIN;
  for (int d = 0; d < DIN; d += 4){
    const float4 xv = *(const float4*)(xr + d);
    const float* w0 = wst + d*16;
#pragma unroll
    for (int c = 0; c < 16; ++c){
      acc[c] = fmaf(xv.x, w0[c],      acc[c]);
      acc[c] = fmaf(xv.y, w0[16+c],   acc[c]);
      acc[c] = fmaf(xv.z, w0[32+c],   acc[c]);
      acc[c] = fmaf(xv.w, w0[48+c],   acc[c]);
    }
  }
#pragma unroll
  for (int h = 0; h < NHEAD; ++h){
    sbuf[n*NHEAD + h] = acc[h];
    tbuf[n*NHEAD + h] = acc[8 + h];
  }
}

// gatW0/1/2 transpose+convert; z selects. z=0 writes duplicated cols [1024][128]
__global__ __launch_bounds__(256) void transpose_all_kernel(
    const float* __restrict__ W0, const float* __restrict__ W1,
    const float* __restrict__ W2,
    u16* __restrict__ T0, u16* __restrict__ T1, u16* __restrict__ T2){
  const int z = blockIdx.z;
  const float* W = (z==0)?W0:(z==1)?W1:W2;
  u16* T = (z==0)?T0:(z==1)?T1:T2;
  const int K = (z==0)?DIN:HDIM;
  const int bk = blockIdx.y*32;
  if (bk >= K) return;
  __shared__ float t[32][33];
  int bn = blockIdx.x*32;
  int lx = threadIdx.x & 31, ly = threadIdx.x >> 5;   // 32 x 8
#pragma unroll
  for (int r = 0; r < 32; r += 8)
    t[ly+r][lx] = W[(size_t)(bk+ly+r)*HDIM + bn + lx];
  __syncthreads();
#pragma unroll
  for (int r = 0; r < 32; r += 8){
    const u16 v = f2bf(t[lx][ly+r]);
    if (z == 0){
      const size_t base = (size_t)(bn+ly+r)*128 + bk + lx;
      T[base] = v; T[base + 64] = v;           // duplicated for hi/lo K=128
    } else {
      T[(size_t)(bn+ly+r)*K + bk + lx] = v;
    }
  }
}

// ---------------- CSR scan (block 0, writes self-loops) + gcnt scan -------
__global__ __launch_bounds__(1024) void scan_pair_kernel(const int* __restrict__ cnt,
    int* __restrict__ rowptr, int* __restrict__ cursor, int* __restrict__ colidx,
    const int* __restrict__ gcnt, int* __restrict__ goff){
  if (blockIdx.x == 1){
    if (threadIdx.x == 0){
      int s = 0;
      for (int g = 0; g < NGRAPH; ++g){ goff[g] = s; s += gcnt[g]; }
      goff[NGRAPH] = s;
    }
    return;
  }
  __shared__ int wsum[16];
  __shared__ int carry_s;
  const int tid = threadIdx.x, lane = tid & 63, wv = tid >> 6;
  if (tid == 0){ carry_s = 0; rowptr[0] = 0; }
  __syncthreads();
  for (int base = 0; base < N_NODES; base += 1024){
    int i = base + tid;
    int v = (i < N_NODES) ? cnt[i] + 1 : 0;      // +1 self-loop
    int s = v;
#pragma unroll
    for (int off = 1; off < 64; off <<= 1){
      int t = __shfl_up(s, off);
      if (lane >= off) s += t;
    }
    if (lane == 63) wsum[wv] = s;
    __syncthreads();
    if (wv == 0 && lane < 16){
      int ws = wsum[lane];
#pragma unroll
      for (int off = 1; off < 16; off <<= 1){
        int t = __shfl_up(ws, off);
        if (lane >= off) ws += t;
      }
      wsum[lane] = ws;
    }
    __syncthreads();
    int incl = s + ((wv > 0) ? wsum[wv-1] : 0) + carry_s;
    if (i < N_NODES){
      rowptr[i+1] = incl;
      const int slot = incl - v;       // row base
      colidx[slot] = i;                // self-loop FIRST (R5 ordering anchor)
      cursor[i] = slot + 1;            // edges fill after
    }
    __syncthreads();
    if (tid == 1023) carry_s = incl;
    __syncthreads();
  }
}

__global__ __launch_bounds__(256) void fill_edges_kernel(const int* __restrict__ ei,
    int* __restrict__ cursor, int* __restrict__ colidx){
  int e = blockIdx.x*256 + threadIdx.x;
  if (e < N_EDGES){
    int s = ei[e], d = ei[N_EDGES + e];
    int p = atomicAdd(&cursor[d], 1);
    colidx[p] = s;
  }
}

// ---------------- bf16 MFMA GEMM (shared body, BK=32) ----------------
// emode=0: bf16 C (+optional fused s/t). emode=1: elu(C+bias)+0.1*noise->bf16
__device__ __forceinline__ void gemm_tile(const u16* __restrict__ A,
    const u16* __restrict__ BT, const float* __restrict__ bias,
    u16* __restrict__ Cb, int M, int K, int bm, int bn,
    u16* As, u16* Bs,
    const float* __restrict__ asrc, const float* __restrict__ adst,
    float* __restrict__ sbuf, float* __restrict__ tbuf,
    const int emode, const u32 seed){
  const int tid = threadIdx.x;
  const int lane = tid & 63, w = tid >> 6;
  const int wm = (w & 1)*64, wn = (w >> 1)*64;

  const int cid0 = tid, cid1 = 256 + tid;
  const int r0 = cid0 & 127, kc0 = cid0 >> 7;
  const int r1 = cid1 & 127, kc1 = cid1 >> 7;
  int ar0 = bm + r0; if (ar0 >= M) ar0 = M - 1;
  int ar1 = bm + r1; if (ar1 >= M) ar1 = M - 1;
  const u16* ag0 = A + (size_t)ar0*K + kc0*8;
  const u16* ag1 = A + (size_t)ar1*K + kc1*8;
  const u16* bg0 = BT + (size_t)(bn + r0)*K + kc0*8;
  const u16* bg1 = BT + (size_t)(bn + r1)*K + kc1*8;
  u16* al0 = As + cid0*8;  u16* al1 = As + cid1*8;
  u16* bl0 = Bs + cid0*8;  u16* bl1 = Bs + cid1*8;

  const int rowl = lane & 15, kg = lane >> 4;
  const bfx8* ap = (const bfx8*)(As + ((size_t)kg*128 + wm + rowl)*8);
  const bfx8* bp = (const bfx8*)(Bs + ((size_t)kg*128 + wn + rowl)*8);

  f32x4 acc[4][4] = {};                       // [j][i] (operand-swapped)
  for (int k0 = 0; k0 < K; k0 += 32){
    g2l16(ag0 + k0, al0);
    g2l16(ag1 + k0, al1);
    g2l16(bg0 + k0, bl0);
    g2l16(bg1 + k0, bl1);
    __syncthreads();
    bfx8 af[4], bfr[4];
#pragma unroll
    for (int i = 0; i < 4; ++i){ af[i] = ap[i*16]; bfr[i] = bp[i*16]; }
#pragma unroll
    for (int i = 0; i < 4; ++i)
#pragma unroll
      for (int j = 0; j < 4; ++j)
        acc[j][i] = __builtin_amdgcn_mfma_f32_16x16x32_bf16(bfr[j], af[i], acc[j][i], 0, 0, 0);
    __syncthreads();
  }

  const int quad = lane >> 4;
  const bool dost = (sbuf != nullptr);
  const int head = bn >> 7;
  float sl[4] = {0.f,0.f,0.f,0.f}, tl[4] = {0.f,0.f,0.f,0.f};
#pragma unroll
  for (int j = 0; j < 4; ++j){
    const int col0 = bn + wn + j*16 + quad*4;
    float4 bv = make_float4(0.f,0.f,0.f,0.f);
    if (bias) bv = *(const float4*)(bias + col0);
    float4 av = make_float4(0.f,0.f,0.f,0.f), dv = av;
    if (dost){
      const int d0 = col0 - bn;                  // head-local dim
      av = *(const float4*)(asrc + head*DHID + d0);
      dv = *(const float4*)(adst + head*DHID + d0);
    }
#pragma unroll
    for (int i = 0; i < 4; ++i){
      const int row = bm + wm + i*16 + rowl;
      if (emode == 1){
        if (row < M){
          float v0 = acc[j][i][0] + bv.x;
          float v1 = acc[j][i][1] + bv.y;
          float v2 = acc[j][i][2] + bv.z;
          float v3 = acc[j][i][3] + bv.w;
          v0 = (v0 > 0.f) ? v0 : __expf(v0) - 1.0f;
          v1 = (v1 > 0.f) ? v1 : __expf(v1) - 1.0f;
          v2 = (v2 > 0.f) ? v2 : __expf(v2) - 1.0f;
          v3 = (v3 > 0.f) ? v3 : __expf(v3) - 1.0f;
          const u32 ib = (u32)row*HDIM + (u32)col0;
          v0 = fmaf(0.1f, jax_normal(seed, ib+0u), v0);
          v1 = fmaf(0.1f, jax_normal(seed, ib+1u), v1);
          v2 = fmaf(0.1f, jax_normal(seed, ib+2u), v2);
          v3 = fmaf(0.1f, jax_normal(seed, ib+3u), v3);
          uint2 pk;
          pk.x = (u32)f2bf(v0) | ((u32)f2bf(v1) << 16);
          pk.y = (u32)f2bf(v2) | ((u32)f2bf(v3) << 16);
          *(uint2*)(Cb + (size_t)row*HDIM + col0) = pk;
        }
      } else {
        const u16 p0 = f2bf(acc[j][i][0] + bv.x);
        const u16 p1 = f2bf(acc[j][i][1] + bv.y);
        const u16 p2 = f2bf(acc[j][i][2] + bv.z);
        const u16 p3 = f2bf(acc[j][i][3] + bv.w);
        if (row < M){
          uint2 pk;
          pk.x = (u32)p0 | ((u32)p1 << 16);
          pk.y = (u32)p2 | ((u32)p3 << 16);
          *(uint2*)(Cb + (size_t)row*HDIM + col0) = pk;
        }
        if (dost){
          const float c0 = bf2f(p0), c1 = bf2f(p1), c2 = bf2f(p2), c3 = bf2f(p3);
          sl[i] = fmaf(c0, av.x, fmaf(c1, av.y, fmaf(c2, av.z, fmaf(c3, av.w, sl[i]))));
          tl[i] = fmaf(c0, dv.x, fmaf(c1, dv.y, fmaf(c2, dv.z, fmaf(c3, dv.w, tl[i]))));
        }
      }
    }
  }
  if (dost){
#pragma unroll
    for (int i = 0; i < 4; ++i){
      sl[i] += __shfl_xor(sl[i], 16); sl[i] += __shfl_xor(sl[i], 32);
      tl[i] += __shfl_xor(tl[i], 16); tl[i] += __shfl_xor(tl[i], 32);
    }
    // cross-wave (wn) combine via dead As buffer
    float* sred = (float*)As;        // [128]
    float* tred = sred + 128;        // [128]
    if ((w >> 1) == 0 && quad == 0){
#pragma unroll
      for (int i = 0; i < 4; ++i){
        const int rl = wm + i*16 + rowl;
        sred[rl] = sl[i]; tred[rl] = tl[i];
      }
    }
    __syncthreads();
    if ((w >> 1) == 1 && quad == 0){
#pragma unroll
      for (int i = 0; i < 4; ++i){
        const int rl = wm + i*16 + rowl;
        const int row = bm + rl;
        if (row < M){
          sbuf[row*NHEAD + head] = sred[rl] + sl[i];
          tbuf[row*NHEAD + head] = tred[rl] + tl[i];
        }
      }
    }
  }
}

// main GEMM: XCD-aware swizzle (R10), fused st epilogue
__global__ __launch_bounds__(256) void gemm_bf16(
    const u16* __restrict__ A, const u16* __restrict__ BT,
    const float* __restrict__ bias, u16* __restrict__ Cb, int M, int K,
    const float* __restrict__ asrc, const float* __restrict__ adst,
    float* __restrict__ sbuf, float* __restrict__ tbuf){
  __shared__ __align__(16) u16 As[4*128*8];   // 8 KB
  __shared__ __align__(16) u16 Bs[4*128*8];   // 8 KB
  const int kblk = blockIdx.y*8 + blockIdx.x;
  const int xc = kblk & 7, bq = (kblk >> 3) & 7, gq = kblk >> 6;
  const int bmi = gq*8 + xc;                  // row-tile index
  const int mt = (M + 127) >> 7;
  if (bmi >= mt) return;
  gemm_tile(A, BT, bias, Cb, M, K, bmi*128, bq*128, As, Bs,
            asrc, adst, sbuf, tbuf, 0, 0u);
}

// L0 transform GEMM: per-head [N,128(hi|lo)] @ W0dup + bias -> elu -> noise
__global__ __launch_bounds__(256) void gemm_l0t(
    const u16* __restrict__ agg2, const u16* __restrict__ BT,
    const float* __restrict__ bias, u16* __restrict__ Cb, u32 seed){
  __shared__ __align__(16) u16 As[4*128*8];
  __shared__ __align__(16) u16 Bs[4*128*8];
  const int head = blockIdx.x;                // 0..7
  const int bm = blockIdx.y*128;
  gemm_tile(agg2 + (size_t)head*N_NODES*128, BT, bias, Cb, N_NODES, 128,
            bm, head*128, As, Bs, nullptr, nullptr, nullptr, nullptr,
            1, seed);
}

// weight-fusion GEMMs (z=0,1) + fused-bias reductions (z=2) in one launch
__global__ __launch_bounds__(256) void wf_bias_kernel(
    const u16* __restrict__ A0, const u16* __restrict__ B0, u16* __restrict__ C0,
    const u16* __restrict__ A1, const u16* __restrict__ B1, u16* __restrict__ C1,
    const float* __restrict__ bb0, const u16* __restrict__ gwt0,
    const float* __restrict__ bb1, const u16* __restrict__ gwt1,
    float* __restrict__ fb0, float* __restrict__ fb1){
  __shared__ __align__(16) u16 As[4*128*8];
  __shared__ __align__(16) u16 Bs[4*128*8];
  if (blockIdx.z < 2){
    const u16* A = blockIdx.z ? A1 : A0;
    const u16* B = blockIdx.z ? B1 : B0;
    u16* C = blockIdx.z ? C1 : C0;
    gemm_tile(A, B, nullptr, C, HDIM, HDIM, blockIdx.y*128, blockIdx.x*128,
              As, Bs, nullptr, nullptr, nullptr, nullptr, 0, 0u);
  } else {
    const int kb = blockIdx.y*8 + blockIdx.x;          // 0..63
    const int wv = threadIdx.x >> 6, lane = threadIdx.x & 63;
    for (int idx = kb*4 + wv; idx < 2*HDIM; idx += 256){
      const int set = idx >> 10, n = idx & (HDIM-1);
      const float* bb = set ? bb1 : bb0;
      const u16* row = (set ? gwt1 : gwt0) + (size_t)n*HDIM + lane*16;
      const float* bp = bb + lane*16;
      float acc = 0.f;
#pragma unroll
      for (int k = 0; k < 16; ++k) acc = fmaf(bp[k], bf2f(row[k]), acc);
      for (int off = 32; off > 0; off >>= 1) acc += __shfl_down(acc, off);
      if (lane == 0) (set ? fb1 : fb0)[n] = acc;
    }
  }
}

// ---------------- GAT aggregation core (wave-per-node, R2 structure) ------
// lane layout, e-phase : lane = jsub*8 + hh  (8 edge slots x 8 heads)
// lane layout, agg     : lane owns dims [lane*16, lane*16+16)  -> head hA=lane>>3
// Computes o[16] = elu(agg/denom + bias) for node n, dims lane*16..+16.
__device__ __forceinline__ void gat_core(const u16* __restrict__ hlin,
    const float* __restrict__ sbuf, const float* __restrict__ tbuf,
    const int* __restrict__ rowptr, const int* __restrict__ colidx,
    const float* __restrict__ bias, const int n, const int lane,
    float o[16]){
  const int jsub = lane >> 3;
  const int hh   = lane & 7;
  const int hA   = lane >> 3;
  const int row0 = rowptr[n];
  const int deg  = rowptr[n+1] - row0; // >=1 (self-loop)
  const float tn = tbuf[n*NHEAD + hh];
  const char* hl = (const char*)hlin;
  const u32 lb   = (u32)lane << 5;     // 32 bytes per lane

  f32x2 acc[8] = {};                   // 16 dims
  float m_run = -INFINITY, d_run = 0.f;

  for (int c = 0; c < deg; c += 8){
    const int ne = min(8, deg - c);
    // ---- e-phase: this lane handles edge (c+jsub), head hh ----
    const int jj = (jsub < ne) ? jsub : (ne - 1);      // clamp (value unused)
    const int srcv = colidx[row0 + c + jj];
    float e = sbuf[srcv*NHEAD + hh] + tn;
    e = (e > 0.f) ? e : 0.2f*e;                        // leaky_relu 0.2
    if (jsub >= ne) e = -INFINITY;
    float mc = e;
    mc = fmaxf(mc, __shfl_xor(mc, 8));
    mc = fmaxf(mc, __shfl_xor(mc, 16));
    mc = fmaxf(mc, __shfl_xor(mc, 32));
    const float mnew = fmaxf(m_run, mc);
    const float w = __expf(e - mnew);                  // exp(-inf)=0 for pads
    float ws = w;
    ws += __shfl_xor(ws, 8);
    ws += __shfl_xor(ws, 16);
    ws += __shfl_xor(ws, 32);
    const float r = (m_run == -INFINITY) ? 0.0f : __expf(m_run - mnew);
    d_run = fmaf(d_run, r, ws);
    m_run = mnew;
    // ---- rescale accumulators for this lane's head ----
    const float rA = __shfl(r, hA);
    const f32x2 r2 = {rA, rA};
#pragma unroll
    for (int q = 0; q < 8; ++q) acc[q] *= r2;
    // ---- gather + weighted accumulate (2 edges / iter) ----
    int j = 0;
    for (; j + 2 <= ne; j += 2){
      const int s0 = __builtin_amdgcn_readlane(srcv, j*8);
      const int s1 = __builtin_amdgcn_readlane(srcv, j*8 + 8);
      const float w0 = __shfl(w, j*8 + hA);
      const float w1 = __shfl(w, j*8 + 8 + hA);
      const char* rp0 = hl + (((size_t)(u32)s0) << 11);
      const char* rp1 = hl + (((size_t)(u32)s1) << 11);
      const uint4 a0 = *(const uint4*)(rp0 + lb);
      const uint4 a1 = *(const uint4*)(rp0 + lb + 16);
      const uint4 b0 = *(const uint4*)(rp1 + lb);
      const uint4 b1 = *(const uint4*)(rp1 + lb + 16);
      const f32x2 w02 = {w0, w0}, w12 = {w1, w1};
      acc[0] = __builtin_elementwise_fma(w02, up2(a0.x), acc[0]);
      acc[1] = __builtin_elementwise_fma(w02, up2(a0.y), acc[1]);
      acc[2] = __builtin_elementwise_fma(w02, up2(a0.z), acc[2]);
      acc[3] = __builtin_elementwise_fma(w02, up2(a0.w), acc[3]);
      acc[4] = __builtin_elementwise_fma(w02, up2(a1.x), acc[4]);
      acc[5] = __builtin_elementwise_fma(w02, up2(a1.y), acc[5]);
      acc[6] = __builtin_elementwise_fma(w02, up2(a1.z), acc[6]);
      acc[7] = __builtin_elementwise_fma(w02, up2(a1.w), acc[7]);
      acc[0] = __builtin_elementwise_fma(w12, up2(b0.x), acc[0]);
      acc[1] = __builtin_elementwise_fma(w12, up2(b0.y), acc[1]);
      acc[2] = __builtin_elementwise_fma(w12, up2(b0.z), acc[2]);
      acc[3] = __builtin_elementwise_fma(w12, up2(b0.w), acc[3]);
      acc[4] = __builtin_elementwise_fma(w12, up2(b1.x), acc[4]);
      acc[5] = __builtin_elementwise_fma(w12, up2(b1.y), acc[5]);
      acc[6] = __builtin_elementwise_fma(w12, up2(b1.z), acc[6]);
      acc[7] = __builtin_elementwise_fma(w12, up2(b1.w), acc[7]);
    }
    if (j < ne){
      const int s0 = __builtin_amdgcn_readlane(srcv, j*8);
      const float w0 = __shfl(w, j*8 + hA);
      const char* rp0 = hl + (((size_t)(u32)s0) << 11);
      const uint4 a0 = *(const uint4*)(rp0 + lb);
      const uint4 a1 = *(const uint4*)(rp0 + lb + 16);
      const f32x2 w02 = {w0, w0};
      acc[0] = __builtin_elementwise_fma(w02, up2(a0.x), acc[0]);
      acc[1] = __builtin_elementwise_fma(w02, up2(a0.y), acc[1]);
      acc[2] = __builtin_elementwise_fma(w02, up2(a0.z), acc[2]);
      acc[3] = __builtin_elementwise_fma(w02, up2(a0.w), acc[3]);
      acc[4] = __builtin_elementwise_fma(w02, up2(a1.x), acc[4]);
      acc[5] = __builtin_elementwise_fma(w02, up2(a1.y), acc[5]);
      acc[6] = __builtin_elementwise_fma(w02, up2(a1.z), acc[6]);
      acc[7] = __builtin_elementwise_fma(w02, up2(a1.w), acc[7]);
    }
  }

  // ---- epilogue: normalize + bias + elu ----
  const float dA = __shfl(d_run, hA);
  const float invA = 1.0f / fmaxf(dA, 1e-16f);
#pragma unroll
  for (int q = 0; q < 8; ++q){ o[2*q] = acc[q].x; o[2*q+1] = acc[q].y; }
  const float4* bp = (const float4*)(bias + lane*16);
#pragma unroll
  for (int q = 0; q < 4; ++q){
    const float4 bv = bp[q];
    o[4*q+0] = fmaf(o[4*q+0], invA, bv.x);
    o[4*q+1] = fmaf(o[4*q+1], invA, bv.y);
    o[4*q+2] = fmaf(o[4*q+2], invA, bv.z);
    o[4*q+3] = fmaf(o[4*q+3], invA, bv.w);
  }
#pragma unroll
  for (int k = 0; k < 16; ++k)
    o[k] = (o[k] > 0.f) ? o[k] : __expf(o[k]) - 1.0f;   // elu (fast)
}

// noise variant (layers 0/1): + 0.1*threefry noise -> bf16 out. No LDS.
__global__ __launch_bounds__(256) void gat_agg_noise_kernel(
    const u16* __restrict__ hlin,
    const float* __restrict__ sbuf, const float* __restrict__ tbuf,
    const int* __restrict__ rowptr, const int* __restrict__ colidx,
    const float* __restrict__ bias, u16* __restrict__ outbf, u32 seed){
  const int tid  = threadIdx.x;
  const int lane = tid & 63;
  const int n    = blockIdx.x*4 + (tid >> 6);
  float o[16];
  gat_core(hlin, sbuf, tbuf, rowptr, colidx, bias, n, lane, o);
  const u32 ib = (u32)n*HDIM + (u32)lane*16u;
  u32 pk[8];
#pragma unroll
  for (int q = 0; q < 8; ++q){
    const float v0 = fmaf(0.1f, jax_normal(seed, ib + 2u*q + 0u), o[2*q+0]);
    const float v1 = fmaf(0.1f, jax_normal(seed, ib + 2u*q + 1u), o[2*q+1]);
    pk[q] = (u32)f2bf(v0) | ((u32)f2bf(v1) << 16);
  }
  uint4* dst = (uint4*)(outbf + (size_t)n*HDIM + lane*16);
  dst[0] = make_uint4(pk[0], pk[1], pk[2], pk[3]);
  dst[1] = make_uint4(pk[4], pk[5], pk[6], pk[7]);
}

// pool variant (layer 2): block LDS-reduce + atomics into 8-way replicated
// gsum8[rep][G][HDIM] (rep = blockIdx&7 keeps each replica's lines on ~1 XCD).
__global__ __launch_bounds__(256) void gat_agg_pool_kernel(
    const u16* __restrict__ hlin,
    const float* __restrict__ sbuf, const float* __restrict__ tbuf,
    const int* __restrict__ rowptr, const int* __restrict__ colidx,
    const float* __restrict__ bias,
    const int* __restrict__ batch, float* __restrict__ gsum8){
  __shared__ float red[4][HDIM];       // 16 KB
  const int tid  = threadIdx.x;
  const int lane = tid & 63;
  const int wv   = tid >> 6;
  const int n    = blockIdx.x*4 + wv;
  float o[16];
  gat_core(hlin, sbuf, tbuf, rowptr, colidx, bias, n, lane, o);
  float* rw = &red[wv][lane*16];
#pragma unroll
  for (int q = 0; q < 4; ++q)
    *(float4*)(rw + q*4) = make_float4(o[4*q], o[4*q+1], o[4*q+2], o[4*q+3]);
  __syncthreads();
  const int rep = blockIdx.x & 7;
  const int g0 = batch[blockIdx.x*4];
  const int g3 = batch[blockIdx.x*4 + 3];
  if (g0 == g3){
    const int d = tid*4;
    float4 s;
    s.x = red[0][d+0] + red[1][d+0] + red[2][d+0] + red[3][d+0];
    s.y = red[0][d+1] + red[1][d+1] + red[2][d+1] + red[3][d+1];
    s.z = red[0][d+2] + red[1][d+2] + red[2][d+2] + red[3][d+2];
    s.w = red[0][d+3] + red[1][d+3] + red[2][d+3] + red[3][d+3];
    float* gp = gsum8 + ((size_t)rep*NGRAPH + g0)*HDIM + d;
    atomicAdd(gp+0, s.x); atomicAdd(gp+1, s.y);
    atomicAdd(gp+2, s.z); atomicAdd(gp+3, s.w);
  } else {
    const int gn = batch[n];
    float* gp = gsum8 + ((size_t)rep*NGRAPH + gn)*HDIM + lane*16;
#pragma unroll
    for (int k = 0; k < 16; ++k) atomicAdd(gp + k, o[k]);
  }
}

// ---------------- L0 aggregation over x (wave-per-node) -------------------
// e-phase layout identical to gat_core. Agg: lane owns head hA=lane>>3 and
// x dims [(lane&7)*8, +8). Gathers 128B bf16 x-rows (L2-resident).
// Output agg2[h][n][128]: cols 0:64 = bf16-hi, 64:128 = bf16-lo of fp32 agg.
__global__ __launch_bounds__(256) void agg_x_kernel(const u16* __restrict__ xbf,
    const float* __restrict__ sbuf, const float* __restrict__ tbuf,
    const int* __restrict__ rowptr, const int* __restrict__ colidx,
    u16* __restrict__ agg2){
  const int tid  = threadIdx.x;
  const int lane = tid & 63;
  const int n    = blockIdx.x*4 + (tid >> 6);
  const int jsub = lane >> 3;
  const int hh   = lane & 7;
  const int hA   = lane >> 3;
  const int row0 = rowptr[n];
  const int deg  = rowptr[n+1] - row0;
  const float tn = tbuf[n*NHEAD + hh];
  const char* xb = (const char*)xbf;
  const u32 lb   = (u32)(lane & 7) << 4;   // 16B dim-group within 128B row

  f32x2 acc[4] = {};                       // 8 dims
  float m_run = -INFINITY, d_run = 0.f;

  for (int c = 0; c < deg; c += 8){
    const int ne = min(8, deg - c);
    const int jj = (jsub < ne) ? jsub : (ne - 1);
    const int srcv = colidx[row0 + c + jj];
    float e = sbuf[srcv*NHEAD + hh] + tn;
    e = (e > 0.f) ? e : 0.2f*e;
    if (jsub >= ne) e = -INFINITY;
    float mc = e;
    mc = fmaxf(mc, __shfl_xor(mc, 8));
    mc = fmaxf(mc, __shfl_xor(mc, 16));
    mc = fmaxf(mc, __shfl_xor(mc, 32));
    const float mnew = fmaxf(m_run, mc);
    const float w = __expf(e - mnew);
    float ws = w;
    ws += __shfl_xor(ws, 8);
    ws += __shfl_xor(ws, 16);
    ws += __shfl_xor(ws, 32);
    const float r = (m_run == -INFINITY) ? 0.0f : __expf(m_run - mnew);
    d_run = fmaf(d_run, r, ws);
    m_run = mnew;
    const float rA = __shfl(r, hA);
    const f32x2 r2 = {rA, rA};
#pragma unroll
    for (int q = 0; q < 4; ++q) acc[q] *= r2;
    int j = 0;
    for (; j + 2 <= ne; j += 2){
      const int s0 = __builtin_amdgcn_readlane(srcv, j*8);
      const int s1 = __builtin_amdgcn_readlane(srcv, j*8 + 8);
      const float w0 = __shfl(w, j*8 + hA);
      const float w1 = __shfl(w, j*8 + 8 + hA);
      const uint4 a0 = *(const uint4*)(xb + (((size_t)(u32)s0) << 7) + lb);
      const uint4 b0 = *(const uint4*)(xb + (((size_t)(u32)s1) << 7) + lb);
      const f32x2 w02 = {w0, w0}, w12 = {w1, w1};
      acc[0] = __builtin_elementwise_fma(w02, up2(a0.x), acc[0]);
      acc[1] = __builtin_elementwise_fma(w02, up2(a0.y), acc[1]);
      acc[2] = __builtin_elementwise_fma(w02, up2(a0.z), acc[2]);
      acc[3] = __builtin_elementwise_fma(w02, up2(a0.w), acc[3]);
      acc[0] = __builtin_elementwise_fma(w12, up2(b0.x), acc[0]);
      acc[1] = __builtin_elementwise_fma(w12, up2(b0.y), acc[1]);
      acc[2] = __builtin_elementwise_fma(w12, up2(b0.z), acc[2]);
      acc[3] = __builtin_elementwise_fma(w12, up2(b0.w), acc[3]);
    }
    if (j < ne){
      const int s0 = __builtin_amdgcn_readlane(srcv, j*8);
      const float w0 = __shfl(w, j*8 + hA);
      const uint4 a0 = *(const uint4*)(xb + (((size_t)(u32)s0) << 7) + lb);
      const f32x2 w02 = {w0, w0};
      acc[0] = __builtin_elementwise_fma(w02, up2(a0.x), acc[0]);
      acc[1] = __builtin_elementwise_fma(w02, up2(a0.y), acc[1]);
      acc[2] = __builtin_elementwise_fma(w02, up2(a0.z), acc[2]);
      acc[3] = __builtin_elementwise_fma(w02, up2(a0.w), acc[3]);
    }
  }

  // ---- epilogue: normalize, hi/lo bf16 split, store ----
  const float dA = __shfl(d_run, hA);
  const float invA = 1.0f / fmaxf(dA, 1e-16f);
  float v[8];
#pragma unroll
  for (int q = 0; q < 4; ++q){ v[2*q] = acc[q].x*invA; v[2*q+1] = acc[q].y*invA; }
  u32 hp[4], lp[4];
#pragma unroll
  for (int q = 0; q < 4; ++q){
    const u16 h0 = f2bf(v[2*q]),   h1 = f2bf(v[2*q+1]);
    const u16 l0 = f2bf(v[2*q]   - bf2f(h0));
    const u16 l1 = f2bf(v[2*q+1] - bf2f(h1));
    hp[q] = (u32)h0 | ((u32)h1 << 16);
    lp[q] = (u32)l0 | ((u32)l1 << 16);
  }
  u16* base = agg2 + ((size_t)hA*N_NODES + (size_t)n)*128 + (lane & 7)*8;
  *(uint4*)(base)      = make_uint4(hp[0], hp[1], hp[2], hp[3]);
  *(uint4*)(base + 64) = make_uint4(lp[0], lp[1], lp[2], lp[3]);
}

// ---------------- pool stage 2: mean + classifier (reads 2MB gsum8) -------
__global__ __launch_bounds__(256) void pool_clf_kernel(const float* __restrict__ gsum8,
    const int* __restrict__ gcnt,
    const float* __restrict__ W1, const float* __restrict__ b1,
    const float* __restrict__ W2, const float* __restrict__ b2,
    float* __restrict__ out){
  __shared__ float gs[HDIM];
  __shared__ float z[DHID];
  const int g = blockIdx.x, tid = threadIdx.x;
  const int cb = tid*4;
  const float invc = 1.0f / fmaxf((float)gcnt[g], 1.0f);
  float4 s = make_float4(0.f,0.f,0.f,0.f);
#pragma unroll
  for (int r = 0; r < 8; ++r){
    const float4 v = *(const float4*)(gsum8 + ((size_t)r*NGRAPH + g)*HDIM + cb);
    s.x += v.x; s.y += v.y; s.z += v.z; s.w += v.w;
  }
  gs[cb+0] = s.x*invc; gs[cb+1] = s.y*invc;
  gs[cb+2] = s.z*invc; gs[cb+3] = s.w*invc;
  __syncthreads();
  if (tid < DHID){
    float a = b1[tid];
    for (int k = 0; k < HDIM; ++k) a = fmaf(gs[k], W1[k*DHID + tid], a);
    z[tid] = fmaxf(a, 0.0f);
  }
  __syncthreads();
  if (tid < 2){
    float o = b2[tid];
    for (int k = 0; k < DHID; ++k) o = fmaf(z[k], W2[k*2 + tid], o);
    out[g*2 + tid] = o;
  }
}

// ---------------- launch ----------------
extern "C" void kernel_launch(void* const* d_in, const int* in_sizes, int n_in,
                              void* d_out, int out_size, void* d_ws, size_t ws_size,
                              hipStream_t stream){
  const float* x      = (const float*)d_in[0];
  const int*   ei     = (const int*)d_in[1];
  const int*   batch  = (const int*)d_in[2];
  const float* gatW[3]  = {(const float*)d_in[3],  (const float*)d_in[7],  (const float*)d_in[11]};
  const float* gatB[3]  = {(const float*)d_in[4],  (const float*)d_in[8],  (const float*)d_in[12]};
  const float* asrc[3]  = {(const float*)d_in[5],  (const float*)d_in[9],  (const float*)d_in[13]};
  const float* adst[3]  = {(const float*)d_in[6],  (const float*)d_in[10], (const float*)d_in[14]};
  const float* bootW[2] = {(const float*)d_in[15], (const float*)d_in[17]};
  const float* bootB[2] = {(const float*)d_in[16], (const float*)d_in[18]};
  const float* clfW1 = (const float*)d_in[19];
  const float* clfb1 = (const float*)d_in[20];
  const float* clfW2 = (const float*)d_in[21];
  const float* clfb2 = (const float*)d_in[22];
  float* outp = (float*)d_out;

  // ---- workspace layout ----
  float* fws  = (float*)d_ws;
  float* hB   = fws;                               // N*HD fp32 (unused; keeps layout)
  float* sbuf = hB + (size_t)N_NODES*HDIM;         // N*H
  float* tbuf = sbuf + (size_t)N_NODES*NHEAD;      // N*H
  float* fbias0 = tbuf + (size_t)N_NODES*NHEAD;    // HD fp32 (bootB0 @ gatW1)
  float* fbias1 = fbias0 + HDIM;                   // HD fp32 (bootB1 @ gatW2)
  u16* xbf    = (u16*)(fbias1 + HDIM);             // N*DIN bf16
  u16* hAbf   = xbf + (size_t)N_NODES*DIN;         // N*HD bf16 (agg2 alias / GEMM out)
  u16* hBbf   = hAbf + (size_t)N_NODES*HDIM;       // N*HD bf16 (GAT+noise out)
  u16* wt[3];
  wt[0] = hBbf + (size_t)N_NODES*HDIM;             // gatW0^T dup [1024,128]
  wt[1] = wt[0] + (size_t)HDIM*128;                // gatW1^T [1024,1024]
  wt[2] = wt[1] + (size_t)HDIM*HDIM;               // gatW2^T
  u16* wnt0   = wt[2] + (size_t)HDIM*HDIM;         // bootW0 bf16 (row-major)
  u16* wnt1   = wnt0 + (size_t)HDIM*HDIM;          // bootW1 bf16 (row-major)
  u16* wf0    = wnt1 + (size_t)HDIM*HDIM;          // (bootW0@gatW1)^T bf16
  u16* wf1    = wf0 + (size_t)HDIM*HDIM;           // (bootW1@gatW2)^T bf16
  int* rowptr = (int*)(wf1 + (size_t)HDIM*HDIM);   // N+1
  int* cursor = rowptr + (N_NODES+1);              // N
  int* colidx = cursor + N_NODES;                  // E_TOT
  int* gcnt   = colidx + E_TOT;                    // G (start of contiguous memset)
  int* cnt    = gcnt + NGRAPH;                     // N (memset cont.)
  float* gsum8 = (float*)(cnt + N_NODES);          // 8*G*HD (memset cont.)
  int* goff   = (int*)(gsum8 + (size_t)8*NGRAPH*HDIM); // G+1
  float* wst  = (float*)(goff + NGRAPH + 1);       // 64*16 fp32

  u16* agg2 = hAbf;                                // [8][N][128] bf16 (hi|lo)

  (void)hipMemsetAsync(gcnt, 0,
      (NGRAPH + N_NODES + (size_t)8*NGRAPH*HDIM)*sizeof(int), stream);

  const int nb_e = (N_EDGES + 255)/256;

  // converts (x, bootW0, bootW1) + CSR/graph counts + wst in one launch
  prep_misc_kernel<<<dim3((E_TOT + 255)/256, 5), 256, 0, stream>>>(
      x, bootW[0], bootW[1], xbf, wnt0, wnt1, ei, batch, cnt, gcnt,
      gatW[0], asrc[0], adst[0], wst);
  // L0 s/t directly from fp32 x (more accurate than bf16-h path)
  st0_kernel<<<(N_NODES + 255)/256, 256, 0, stream>>>(x, wst, sbuf, tbuf);
  transpose_all_kernel<<<dim3(HDIM/32, HDIM/32, 3), 256, 0, stream>>>(
      gatW[0], gatW[1], gatW[2], wt[0], wt[1], wt[2]);
  scan_pair_kernel<<<2, 1024, 0, stream>>>(cnt, rowptr, cursor, colidx, gcnt, goff);
  fill_edges_kernel<<<nb_e, 256, 0, stream>>>(ei, cursor, colidx);

  // fused weights wf[n,k] = sum_m gatW^T[n,m]*bootW[k,m] + fused biases
  wf_bias_kernel<<<dim3(8, 8, 3), 256, 0, stream>>>(
      wt[1], wnt0, wf0, wt[2], wnt1, wf1,
      bootB[0], wt[1], bootB[1], wt[2], fbias0, fbias1);

  // swizzled grid: 8 col-tiles x (row-tiles padded to multiple of 8)
  const int mt = (N_NODES + 127)/128;              // 157
  dim3 gemmGrid(8, (mt + 7)/8*8);                  // (8, 160)

  // ---- L0: aggregate-then-transform (gathers 128B x-rows, L2-resident) ----
  agg_x_kernel<<<N_NODES/4, 256, 0, stream>>>(xbf, sbuf, tbuf, rowptr, colidx,
                                              agg2);
  gemm_l0t<<<dim3(8, mt), 256, 0, stream>>>(agg2, wt[0], gatB[0], hBbf, 100u);

  // L1 (fused boot0+gat1 linear)
  gemm_bf16<<<gemmGrid, 256, 0, stream>>>(hBbf, wf0, fbias0, hAbf, N_NODES, HDIM,
                                          asrc[1], adst[1], sbuf, tbuf);
  gat_agg_noise_kernel<<<N_NODES/4, 256, 0, stream>>>(hAbf, sbuf, tbuf, rowptr,
                                                      colidx, gatB[1], hBbf, 101u);
  // L2 (fused boot1+gat2 linear) + gat with FUSED MEAN-POOL epilogue
  gemm_bf16<<<gemmGrid, 256, 0, stream>>>(hBbf, wf1, fbias1, hAbf, N_NODES, HDIM,
                                          asrc[2], adst[2], sbuf, tbuf);
  gat_agg_pool_kernel<<<N_NODES/4, 256, 0, stream>>>(hAbf, sbuf, tbuf, rowptr,
                                                     colidx, gatB[2], batch, gsum8);

  // classifier (gsum8 holds 8-way replicated per-graph sums)
  pool_clf_kernel<<<NGRAPH, 256, 0, stream>>>(gsum8, gcnt,
                                              clfW1, clfb1, clfW2, clfb2, outp);
}